// Round 9
// baseline (566.696 us; speedup 1.0000x reference)
//
#include <hip/hip_runtime.h>
#include <math.h>

#define NNODES 50000
#define MPAD   50048    // NNODES rounded up to 128
#define D      256
#define K2     512
#define NEDGES 300000
#define NGRAPH 512
#define NLAYERS 3

#define SCB    256
#define NSCB   ((NNODES + SCB - 1) / SCB)   // 196 blocks

typedef __bf16 bf16x8 __attribute__((ext_vector_type(8)));
typedef float  f32x4  __attribute__((ext_vector_type(4)));

__device__ __forceinline__ ushort f2bf(float f) {
    unsigned u = __float_as_uint(f);
    unsigned r = (u + 0x7FFFu + ((u >> 16) & 1u)) >> 16;   // RNE
    return (ushort)r;
}
__device__ __forceinline__ float bf2f(ushort b) {
    return __uint_as_float(((unsigned)b) << 16);
}

__device__ __forceinline__ void stage16(const ushort* g, ushort* l) {
    __builtin_amdgcn_global_load_lds(
        (const __attribute__((address_space(1))) unsigned*)g,
        (__attribute__((address_space(3))) unsigned*)l, 16, 0, 0);
}

// ---------------- CSR build ----------------
__global__ __launch_bounds__(256)
void hist_kernel(const int* __restrict__ dst, int* __restrict__ deg, int nE) {
    int e = blockIdx.x * 256 + threadIdx.x;
    if (e < nE) atomicAdd(&deg[dst[e]], 1);
}

__global__ __launch_bounds__(SCB)
void scan_part_kernel(const int* __restrict__ deg, int* __restrict__ bsum) {
    __shared__ int red[SCB];
    int t = threadIdx.x;
    int i = blockIdx.x * SCB + t;
    red[t] = (i < NNODES) ? deg[i] : 0;
    __syncthreads();
#pragma unroll
    for (int off = SCB / 2; off > 0; off >>= 1) {
        if (t < off) red[t] += red[t + off];
        __syncthreads();
    }
    if (t == 0) bsum[blockIdx.x] = red[0];
}

__global__ __launch_bounds__(256)
void scan_bsum_kernel(const int* __restrict__ bsum, int* __restrict__ boff) {
    __shared__ int p[256];
    int t = threadIdx.x;
    p[t] = (t < NSCB) ? bsum[t] : 0;
    __syncthreads();
    for (int off = 1; off < 256; off <<= 1) {
        int v = (t >= off) ? p[t - off] : 0;
        __syncthreads();
        p[t] += v;
        __syncthreads();
    }
    if (t < NSCB) boff[t] = (t == 0) ? 0 : p[t - 1];
}

__global__ __launch_bounds__(SCB)
void scan_final_kernel(const int* __restrict__ deg, const int* __restrict__ boff,
                       int* __restrict__ row_start, int* __restrict__ cursor) {
    __shared__ int p[SCB];
    int t = threadIdx.x;
    int i = blockIdx.x * SCB + t;
    int v = (i < NNODES) ? deg[i] : 0;
    p[t] = v;
    __syncthreads();
    for (int off = 1; off < SCB; off <<= 1) {
        int u = (t >= off) ? p[t - off] : 0;
        __syncthreads();
        p[t] += u;
        __syncthreads();
    }
    int excl = boff[blockIdx.x] + p[t] - v;
    if (i < NNODES) {
        row_start[i] = excl;
        cursor[i] = excl;
    }
    if (blockIdx.x == 0 && t == 0) row_start[NNODES] = NEDGES;
}

__global__ __launch_bounds__(256)
void fill_kernel(const int* __restrict__ src, const int* __restrict__ dst,
                 int* __restrict__ cursor, int* __restrict__ e_src, int nE) {
    int e = blockIdx.x * 256 + threadIdx.x;
    if (e < nE) {
        int pos = atomicAdd(&cursor[dst[e]], 1);
        e_src[pos] = src[e];
    }
}

// ---------------- graph segment starts (batch sorted) ----------------
__global__ __launch_bounds__(256)
void gstart_kernel(const int* __restrict__ batch, int* __restrict__ gstart) {
    int g = blockIdx.x * 256 + threadIdx.x;
    if (g > NGRAPH) return;
    if (g == NGRAPH) { gstart[g] = NNODES; return; }
    int lo = 0, hi = NNODES;
    while (lo < hi) { int mid = (lo + hi) >> 1; if (batch[mid] < g) lo = mid + 1; else hi = mid; }
    gstart[g] = lo;
}

// ---------------- weight prep: split into hi/lo bf16, [L][n][k] ----------------
__global__ __launch_bounds__(256)
void prep_w_kernel(const float* __restrict__ W_rel, const float* __restrict__ W_root,
                   ushort* __restrict__ Wh, ushort* __restrict__ Wl) {
    int i = blockIdx.x * 256 + threadIdx.x;
    if (i >= NLAYERS * D * K2) return;
    int L = i / (D * K2);
    int rem = i % (D * K2);
    int n = rem / K2;
    int k = rem % K2;
    float v = (k < D) ? W_rel[(size_t)L * D * D + (size_t)k * D + n]
                      : W_root[(size_t)L * D * D + (size_t)(k - D) * D + n];
    ushort hi = f2bf(v);
    float  lo = v - bf2f(hi);
    Wh[i] = hi;
    Wl[i] = f2bf(lo);
}

// ---------------- x f32 -> hi/lo bf16 planes (pad rows zeroed) ----------------
__global__ __launch_bounds__(256)
void cvt_x_kernel(const float* __restrict__ x, ushort* __restrict__ xh,
                  ushort* __restrict__ xl) {
    size_t base = ((size_t)blockIdx.x * 256 + threadIdx.x) * 8;
    if (base >= (size_t)MPAD * D) return;
    ushort h[8], l[8];
    if (base < (size_t)NNODES * D) {
        float4 v0 = *reinterpret_cast<const float4*>(x + base);
        float4 v1 = *reinterpret_cast<const float4*>(x + base + 4);
        float vv[8] = {v0.x, v0.y, v0.z, v0.w, v1.x, v1.y, v1.z, v1.w};
#pragma unroll
        for (int j = 0; j < 8; ++j) {
            h[j] = f2bf(vv[j]);
            l[j] = f2bf(vv[j] - bf2f(h[j]));
        }
    } else {
#pragma unroll
        for (int j = 0; j < 8; ++j) { h[j] = 0; l[j] = 0; }
    }
    *reinterpret_cast<uint4*>(xh + base) = *reinterpret_cast<uint4*>(h);
    *reinterpret_cast<uint4*>(xl + base) = *reinterpret_cast<uint4*>(l);
}

// ---------------- gather-sum over hi/lo planes, writes hi/lo planes ----------------
__global__ __launch_bounds__(256)
void gather_hl_kernel(const ushort* __restrict__ ph, const ushort* __restrict__ pl,
                      const int* __restrict__ row_start, const int* __restrict__ e_src,
                      ushort* __restrict__ gh, ushort* __restrict__ gl) {
    int t = threadIdx.x;
    int n = blockIdx.x * 4 + (t >> 6);
    if (n >= NNODES) return;
    int lane = t & 63;
    int beg = row_start[n], end = row_start[n + 1];
    float a0 = 0.f, a1 = 0.f, a2 = 0.f, a3 = 0.f;
    int j = beg;
    for (; j + 4 <= end; j += 4) {
        int s0 = e_src[j], s1 = e_src[j + 1], s2 = e_src[j + 2], s3 = e_src[j + 3];
        ushort4 h0 = *reinterpret_cast<const ushort4*>(ph + (size_t)s0 * D + lane * 4);
        ushort4 l0 = *reinterpret_cast<const ushort4*>(pl + (size_t)s0 * D + lane * 4);
        ushort4 h1 = *reinterpret_cast<const ushort4*>(ph + (size_t)s1 * D + lane * 4);
        ushort4 l1 = *reinterpret_cast<const ushort4*>(pl + (size_t)s1 * D + lane * 4);
        ushort4 h2 = *reinterpret_cast<const ushort4*>(ph + (size_t)s2 * D + lane * 4);
        ushort4 l2 = *reinterpret_cast<const ushort4*>(pl + (size_t)s2 * D + lane * 4);
        ushort4 h3 = *reinterpret_cast<const ushort4*>(ph + (size_t)s3 * D + lane * 4);
        ushort4 l3 = *reinterpret_cast<const ushort4*>(pl + (size_t)s3 * D + lane * 4);
        a0 += (bf2f(h0.x) + bf2f(l0.x)) + (bf2f(h1.x) + bf2f(l1.x)) +
              (bf2f(h2.x) + bf2f(l2.x)) + (bf2f(h3.x) + bf2f(l3.x));
        a1 += (bf2f(h0.y) + bf2f(l0.y)) + (bf2f(h1.y) + bf2f(l1.y)) +
              (bf2f(h2.y) + bf2f(l2.y)) + (bf2f(h3.y) + bf2f(l3.y));
        a2 += (bf2f(h0.z) + bf2f(l0.z)) + (bf2f(h1.z) + bf2f(l1.z)) +
              (bf2f(h2.z) + bf2f(l2.z)) + (bf2f(h3.z) + bf2f(l3.z));
        a3 += (bf2f(h0.w) + bf2f(l0.w)) + (bf2f(h1.w) + bf2f(l1.w)) +
              (bf2f(h2.w) + bf2f(l2.w)) + (bf2f(h3.w) + bf2f(l3.w));
    }
    for (; j < end; ++j) {
        int s = e_src[j];
        ushort4 h = *reinterpret_cast<const ushort4*>(ph + (size_t)s * D + lane * 4);
        ushort4 l = *reinterpret_cast<const ushort4*>(pl + (size_t)s * D + lane * 4);
        a0 += bf2f(h.x) + bf2f(l.x);
        a1 += bf2f(h.y) + bf2f(l.y);
        a2 += bf2f(h.z) + bf2f(l.z);
        a3 += bf2f(h.w) + bf2f(l.w);
    }
    ushort4 oh, ol;
    oh.x = f2bf(a0); ol.x = f2bf(a0 - bf2f(oh.x));
    oh.y = f2bf(a1); ol.y = f2bf(a1 - bf2f(oh.y));
    oh.z = f2bf(a2); ol.z = f2bf(a2 - bf2f(oh.z));
    oh.w = f2bf(a3); ol.w = f2bf(a3 - bf2f(oh.w));
    *reinterpret_cast<ushort4*>(gh + (size_t)n * D + lane * 4) = oh;
    *reinterpret_cast<ushort4*>(gl + (size_t)n * D + lane * 4) = ol;
}

// ---------------- split-bf16 MFMA GEMM: A direct-to-reg, B 3-buffer counted-vmcnt ----------------
// out = relu([G|X] @ W^T + bias); all operands hi/lo bf16 plane pairs
#define GBM 128
#define GBN 128
#define GBK 32
#define NKS (K2 / GBK)   // 16

__device__ __forceinline__ void load_a_frags(const ushort* __restrict__ ph,
                                             const ushort* __restrict__ pl,
                                             int m0, int wr, int r, int kq, int kk,
                                             bf16x8 ah[4], bf16x8 al[4]) {
#pragma unroll
    for (int m = 0; m < 4; ++m) {
        size_t o = (size_t)(m0 + wr * 64 + m * 16 + r) * D + kk + kq * 8;
        ah[m] = *reinterpret_cast<const bf16x8*>(ph + o);
        al[m] = *reinterpret_cast<const bf16x8*>(pl + o);
    }
}

__global__ __launch_bounds__(256)
void gemm_hl_kernel(const ushort* __restrict__ Gh, const ushort* __restrict__ Gl,
                    const ushort* __restrict__ Xh, const ushort* __restrict__ Xl,
                    const ushort* __restrict__ Wh, const ushort* __restrict__ Wl,
                    const float* __restrict__ bias,
                    ushort* __restrict__ outh, ushort* __restrict__ outl) {
    // B only in LDS: 3 buffers x (h,l) planes x 8 KB = 48 KB -> 3 blocks/CU
    __shared__ ushort B_s[3][2][GBN * GBK];

    int t = threadIdx.x;
    int wid = t >> 6, lane = t & 63;
    int m0 = blockIdx.x * GBM;
    int n0 = blockIdx.y * GBN;
    int wr = wid >> 1, wc = wid & 1;
    int r = lane & 15, kq = lane >> 4;     // fragment coords (row-in-16, k-quarter)

    f32x4 acc[4][4];
#pragma unroll
    for (int m = 0; m < 4; ++m)
#pragma unroll
        for (int n = 0; n < 4; ++n)
            acc[m][n] = (f32x4){0.f, 0.f, 0.f, 0.f};

    // B staging geometry: two 16B chunks per plane per lane (covers 128 rows x 64B)
    // pre-swizzled source: physical chunk sub holds k-half ((row>>1)&3)^sub
    int idxA = wid * 64 + lane;            // 0..255
    int idxB = 256 + idxA;                 // 256..511
    int rowA = idxA >> 2, khA = ((rowA >> 1) & 3) ^ (idxA & 3);
    int rowB = idxB >> 2, khB = ((rowB >> 1) & 3) ^ (idxB & 3);
    size_t loA = (size_t)idxA * 8;
    size_t loB = (size_t)idxB * 8;

    // prologue: stage B for ks=0 (buf 0) and ks=1 (buf 1)
    stage16(Wh + (size_t)(n0 + rowA) * K2 + 0 + khA * 8, &B_s[0][0][loA]);
    stage16(Wh + (size_t)(n0 + rowB) * K2 + 0 + khB * 8, &B_s[0][0][loB]);
    stage16(Wl + (size_t)(n0 + rowA) * K2 + 0 + khA * 8, &B_s[0][1][loA]);
    stage16(Wl + (size_t)(n0 + rowB) * K2 + 0 + khB * 8, &B_s[0][1][loB]);
    stage16(Wh + (size_t)(n0 + rowA) * K2 + GBK + khA * 8, &B_s[1][0][loA]);
    stage16(Wh + (size_t)(n0 + rowB) * K2 + GBK + khB * 8, &B_s[1][0][loB]);
    stage16(Wl + (size_t)(n0 + rowA) * K2 + GBK + khA * 8, &B_s[1][1][loA]);
    stage16(Wl + (size_t)(n0 + rowB) * K2 + GBK + khB * 8, &B_s[1][1][loB]);

    for (int ks = 0; ks < NKS; ++ks) {
        // B[ks] landed when <=4 B-stages outstanding (B[ks+1]'s 4 follow it in
        // builtin program order). Plain A loads are compiler-tracked and may
        // interleave -> vmcnt(4) is conservative-safe. Last step: full drain.
        if (ks < NKS - 1) asm volatile("s_waitcnt vmcnt(4)" ::: "memory");
        else              asm volatile("s_waitcnt vmcnt(0)" ::: "memory");
        __builtin_amdgcn_s_barrier();      // raw: does NOT drain A-reg loads
        __builtin_amdgcn_sched_barrier(0);

        // stage B for ks+2 into buf (ks+2)%3 (its previous readers done pre-barrier)
        if (ks + 2 < NKS) {
            int kn = (ks + 2) * GBK;
            int bn = (ks + 2) % 3;
            stage16(Wh + (size_t)(n0 + rowA) * K2 + kn + khA * 8, &B_s[bn][0][loA]);
            stage16(Wh + (size_t)(n0 + rowB) * K2 + kn + khB * 8, &B_s[bn][0][loB]);
            stage16(Wl + (size_t)(n0 + rowA) * K2 + kn + khA * 8, &B_s[bn][1][loA]);
            stage16(Wl + (size_t)(n0 + rowB) * K2 + kn + khB * 8, &B_s[bn][1][loB]);
        }

        // A fragments: direct global->reg (layout matches MFMA fragment exactly)
        int k0 = ks * GBK;
        const ushort* ph = (k0 < D) ? Gh : Xh;
        const ushort* pl = (k0 < D) ? Gl : Xl;
        int kk = k0 & (D - 1);
        bf16x8 ah[4], al[4], bh[4], bl[4];
        load_a_frags(ph, pl, m0, wr, r, kq, kk, ah, al);

        int cb = ks % 3;
#pragma unroll
        for (int n = 0; n < 4; ++n) {
            int rw = wc * 64 + n * 16 + r;
            int off = rw * GBK + ((((rw >> 1) & 3) ^ kq) * 8);
            bh[n] = *reinterpret_cast<const bf16x8*>(&B_s[cb][0][off]);
            bl[n] = *reinterpret_cast<const bf16x8*>(&B_s[cb][1][off]);
        }
#pragma unroll
        for (int m = 0; m < 4; ++m)
#pragma unroll
            for (int n = 0; n < 4; ++n) {
                acc[m][n] = __builtin_amdgcn_mfma_f32_16x16x32_bf16(ah[m], bh[n], acc[m][n], 0, 0, 0);
                acc[m][n] = __builtin_amdgcn_mfma_f32_16x16x32_bf16(ah[m], bl[n], acc[m][n], 0, 0, 0);
                acc[m][n] = __builtin_amdgcn_mfma_f32_16x16x32_bf16(al[m], bh[n], acc[m][n], 0, 0, 0);
            }
    }

    // epilogue: bias + relu -> hi/lo bf16 planes
#pragma unroll
    for (int n = 0; n < 4; ++n) {
        int col = n0 + wc * 64 + n * 16 + r;
        float bv = bias[col];
#pragma unroll
        for (int m = 0; m < 4; ++m) {
            int rbase = m0 + wr * 64 + m * 16 + kq * 4;
#pragma unroll
            for (int j = 0; j < 4; ++j) {
                int rr = rbase + j;
                if (rr < NNODES) {
                    float v = fmaxf(acc[m][n][j] + bv, 0.f);
                    ushort hv = f2bf(v);
                    outh[(size_t)rr * D + col] = hv;
                    outl[(size_t)rr * D + col] = f2bf(v - bf2f(hv));
                }
            }
        }
    }
}

// ---------------- segmented pool over hi/lo planes (f32 out) ----------------
__global__ __launch_bounds__(256)
void pool_seg_kernel(const ushort* __restrict__ ph, const ushort* __restrict__ pl,
                     const int* __restrict__ gstart, float* __restrict__ pooled) {
    __shared__ float red[4][D];
    int g = blockIdx.x;
    int t = threadIdx.x, wid = t >> 6, lane = t & 63;
    int beg = gstart[g], end = gstart[g + 1];
    float a0 = 0.f, a1 = 0.f, a2 = 0.f, a3 = 0.f;
    for (int rr = beg + wid; rr < end; rr += 4) {
        ushort4 h = *reinterpret_cast<const ushort4*>(ph + (size_t)rr * D + lane * 4);
        ushort4 l = *reinterpret_cast<const ushort4*>(pl + (size_t)rr * D + lane * 4);
        a0 += bf2f(h.x) + bf2f(l.x);
        a1 += bf2f(h.y) + bf2f(l.y);
        a2 += bf2f(h.z) + bf2f(l.z);
        a3 += bf2f(h.w) + bf2f(l.w);
    }
    red[wid][lane * 4 + 0] = a0;
    red[wid][lane * 4 + 1] = a1;
    red[wid][lane * 4 + 2] = a2;
    red[wid][lane * 4 + 3] = a3;
    __syncthreads();
    float s = red[0][t] + red[1][t] + red[2][t] + red[3][t];
    pooled[(size_t)g * D + t] = s;
}

// ---------------- MLP layer 1 (f32) ----------------
__global__ __launch_bounds__(256)
void mlp1_kernel(const float* __restrict__ pooled, const float* __restrict__ W1,
                 const float* __restrict__ b1, float* __restrict__ h) {
    __shared__ float p[D];
    int g = blockIdx.x, t = threadIdx.x;
    p[t] = pooled[(size_t)g * D + t];
    __syncthreads();
    float4 acc = make_float4(0.f, 0.f, 0.f, 0.f);
    for (int k = 0; k < D; ++k) {
        float4 w = *reinterpret_cast<const float4*>(W1 + (size_t)k * 1024 + t * 4);
        float pv = p[k];
        acc.x += pv * w.x; acc.y += pv * w.y; acc.z += pv * w.z; acc.w += pv * w.w;
    }
    float4 b = *reinterpret_cast<const float4*>(b1 + t * 4);
    acc.x = fmaxf(acc.x + b.x, 0.f);
    acc.y = fmaxf(acc.y + b.y, 0.f);
    acc.z = fmaxf(acc.z + b.z, 0.f);
    acc.w = fmaxf(acc.w + b.w, 0.f);
    *reinterpret_cast<float4*>(h + (size_t)g * 1024 + t * 4) = acc;
}

// ---------------- MLP layer 2 (f32) ----------------
__global__ __launch_bounds__(256)
void mlp2_kernel(const float* __restrict__ h, const float* __restrict__ W2,
                 const float* __restrict__ b2, float* __restrict__ out) {
    __shared__ float red[8][32];
    int g = blockIdx.x, t = threadIdx.x;
    int c = t & 31, kc = t >> 5;
    float s = 0.f;
    const float* hr = h + (size_t)g * 1024;
    for (int k = kc * 128; k < kc * 128 + 128; ++k)
        s += hr[k] * W2[(size_t)k * 32 + c];
    red[kc][c] = s;
    __syncthreads();
    if (t < 32) {
        float v = b2[t];
#pragma unroll
        for (int i = 0; i < 8; ++i) v += red[i][t];
        out[(size_t)g * 32 + t] = 1.f / (1.f + expf(-v));
    }
}

extern "C" void kernel_launch(void* const* d_in, const int* in_sizes, int n_in,
                              void* d_out, int out_size, void* d_ws, size_t ws_size,
                              hipStream_t stream) {
    const float* x      = (const float*)d_in[0];
    const int*   ei     = (const int*)d_in[1];
    const int*   batch  = (const int*)d_in[2];
    const float* W_rel  = (const float*)d_in[3];
    const float* W_root = (const float*)d_in[4];
    const float* b_conv = (const float*)d_in[5];
    const float* W1     = (const float*)d_in[6];
    const float* b1     = (const float*)d_in[7];
    const float* W2     = (const float*)d_in[8];
    const float* b2     = (const float*)d_in[9];
    float* outp = (float*)d_out;

    const size_t NF = (size_t)MPAD * D;
    // activation plane pairs: P0 (xh/xl), P1 (yh/yl), G (gh/gl)
    ushort* xh = (ushort*)d_ws;
    ushort* xl = xh + NF;
    ushort* yh = xl + NF;
    ushort* yl = yh + NF;
    ushort* gh = yl + NF;
    ushort* gl = gh + NF;
    ushort* Wh = gl + NF;                    // 3*256*512 each
    ushort* Wl = Wh + (size_t)NLAYERS * D * K2;
    float* pooled = (float*)(Wl + (size_t)NLAYERS * D * K2);
    float* hbuf   = pooled + (size_t)NGRAPH * D;
    int* deg       = (int*)(hbuf + (size_t)NGRAPH * 1024);
    int* row_start = deg + NNODES;           // NNODES+1
    int* cursor    = row_start + NNODES + 1;
    int* e_src     = cursor + NNODES;        // NEDGES
    int* gstart    = e_src + NEDGES;         // NGRAPH+1
    int* bsum      = gstart + NGRAPH + 1;    // NSCB
    int* boff      = bsum + NSCB;            // NSCB

    const int* srcp = ei;
    const int* dstp = ei + NEDGES;

    // CSR build (reused by all layers)
    hipMemsetAsync(deg, 0, NNODES * sizeof(int), stream);
    hist_kernel<<<(NEDGES + 255) / 256, 256, 0, stream>>>(dstp, deg, NEDGES);
    scan_part_kernel<<<NSCB, SCB, 0, stream>>>(deg, bsum);
    scan_bsum_kernel<<<1, 256, 0, stream>>>(bsum, boff);
    scan_final_kernel<<<NSCB, SCB, 0, stream>>>(deg, boff, row_start, cursor);
    fill_kernel<<<(NEDGES + 255) / 256, 256, 0, stream>>>(srcp, dstp, cursor, e_src, NEDGES);
    gstart_kernel<<<3, 256, 0, stream>>>(batch, gstart);

    prep_w_kernel<<<(NLAYERS * D * K2 + 255) / 256, 256, 0, stream>>>(W_rel, W_root, Wh, Wl);
    cvt_x_kernel<<<(int)((NF / 8 + 255) / 256), 256, 0, stream>>>(x, xh, xl);

    int gatherBlocks = (NNODES + 3) / 4;
    dim3 ggrid(MPAD / GBM, D / GBN);

    const ushort* curh = xh; const ushort* curl = xl;
    ushort* nxth = yh;       ushort* nxtl = yl;
    for (int L = 0; L < NLAYERS; ++L) {
        gather_hl_kernel<<<gatherBlocks, 256, 0, stream>>>(curh, curl, row_start, e_src, gh, gl);
        gemm_hl_kernel<<<ggrid, 256, 0, stream>>>(gh, gl, curh, curl,
                                                  Wh + (size_t)L * D * K2,
                                                  Wl + (size_t)L * D * K2,
                                                  b_conv + (size_t)L * D,
                                                  nxth, nxtl);
        // swap P-pair roles
        const ushort* th = curh; const ushort* tl = curl;
        curh = nxth; curl = nxtl;
        nxth = (ushort*)th; nxtl = (ushort*)tl;
        if (L == 0) { nxth = xh; nxtl = xl; }   // after L0: cur=P1, next writes into P0
    }

    pool_seg_kernel<<<NGRAPH, 256, 0, stream>>>(curh, curl, gstart, pooled);
    mlp1_kernel<<<NGRAPH, 256, 0, stream>>>(pooled, W1, b1, hbuf);
    mlp2_kernel<<<NGRAPH, 256, 0, stream>>>(hbuf, W2, b2, outp);
}

// Round 10
// 544.659 us; speedup vs baseline: 1.0405x; 1.0405x over previous
//
#include <hip/hip_runtime.h>
#include <math.h>

#define NNODES 50000
#define MPAD   50048    // NNODES rounded up to 128
#define D      256
#define K2     512
#define NEDGES 300000
#define NGRAPH 512
#define NLAYERS 3

#define SCB    256
#define NSCB   ((NNODES + SCB - 1) / SCB)   // 196 blocks

typedef __bf16 bf16x8 __attribute__((ext_vector_type(8)));
typedef float  f32x4  __attribute__((ext_vector_type(4)));

__device__ __forceinline__ ushort f2bf(float f) {
    unsigned u = __float_as_uint(f);
    unsigned r = (u + 0x7FFFu + ((u >> 16) & 1u)) >> 16;   // RNE
    return (ushort)r;
}
__device__ __forceinline__ float bf2f(ushort b) {
    return __uint_as_float(((unsigned)b) << 16);
}

__device__ __forceinline__ void stage16(const ushort* g, ushort* l) {
    __builtin_amdgcn_global_load_lds(
        (const __attribute__((address_space(1))) unsigned*)g,
        (__attribute__((address_space(3))) unsigned*)l, 16, 0, 0);
}

// ---------------- CSR build ----------------
__global__ __launch_bounds__(256)
void hist_kernel(const int* __restrict__ dst, int* __restrict__ deg, int nE) {
    int e = blockIdx.x * 256 + threadIdx.x;
    if (e < nE) atomicAdd(&deg[dst[e]], 1);
}

__global__ __launch_bounds__(SCB)
void scan_part_kernel(const int* __restrict__ deg, int* __restrict__ bsum) {
    __shared__ int red[SCB];
    int t = threadIdx.x;
    int i = blockIdx.x * SCB + t;
    red[t] = (i < NNODES) ? deg[i] : 0;
    __syncthreads();
#pragma unroll
    for (int off = SCB / 2; off > 0; off >>= 1) {
        if (t < off) red[t] += red[t + off];
        __syncthreads();
    }
    if (t == 0) bsum[blockIdx.x] = red[0];
}

__global__ __launch_bounds__(256)
void scan_bsum_kernel(const int* __restrict__ bsum, int* __restrict__ boff) {
    __shared__ int p[256];
    int t = threadIdx.x;
    p[t] = (t < NSCB) ? bsum[t] : 0;
    __syncthreads();
    for (int off = 1; off < 256; off <<= 1) {
        int v = (t >= off) ? p[t - off] : 0;
        __syncthreads();
        p[t] += v;
        __syncthreads();
    }
    if (t < NSCB) boff[t] = (t == 0) ? 0 : p[t - 1];
}

__global__ __launch_bounds__(SCB)
void scan_final_kernel(const int* __restrict__ deg, const int* __restrict__ boff,
                       int* __restrict__ row_start, int* __restrict__ cursor) {
    __shared__ int p[SCB];
    int t = threadIdx.x;
    int i = blockIdx.x * SCB + t;
    int v = (i < NNODES) ? deg[i] : 0;
    p[t] = v;
    __syncthreads();
    for (int off = 1; off < SCB; off <<= 1) {
        int u = (t >= off) ? p[t - off] : 0;
        __syncthreads();
        p[t] += u;
        __syncthreads();
    }
    int excl = boff[blockIdx.x] + p[t] - v;
    if (i < NNODES) {
        row_start[i] = excl;
        cursor[i] = excl;
    }
    if (blockIdx.x == 0 && t == 0) row_start[NNODES] = NEDGES;
}

__global__ __launch_bounds__(256)
void fill_kernel(const int* __restrict__ src, const int* __restrict__ dst,
                 int* __restrict__ cursor, int* __restrict__ e_src, int nE) {
    int e = blockIdx.x * 256 + threadIdx.x;
    if (e < nE) {
        int pos = atomicAdd(&cursor[dst[e]], 1);
        e_src[pos] = src[e];
    }
}

// ---------------- graph segment starts (batch sorted) ----------------
__global__ __launch_bounds__(256)
void gstart_kernel(const int* __restrict__ batch, int* __restrict__ gstart) {
    int g = blockIdx.x * 256 + threadIdx.x;
    if (g > NGRAPH) return;
    if (g == NGRAPH) { gstart[g] = NNODES; return; }
    int lo = 0, hi = NNODES;
    while (lo < hi) { int mid = (lo + hi) >> 1; if (batch[mid] < g) lo = mid + 1; else hi = mid; }
    gstart[g] = lo;
}

// ---------------- weight prep: split into hi/lo bf16, [L][n][k] ----------------
__global__ __launch_bounds__(256)
void prep_w_kernel(const float* __restrict__ W_rel, const float* __restrict__ W_root,
                   ushort* __restrict__ Wh, ushort* __restrict__ Wl) {
    int i = blockIdx.x * 256 + threadIdx.x;
    if (i >= NLAYERS * D * K2) return;
    int L = i / (D * K2);
    int rem = i % (D * K2);
    int n = rem / K2;
    int k = rem % K2;
    float v = (k < D) ? W_rel[(size_t)L * D * D + (size_t)k * D + n]
                      : W_root[(size_t)L * D * D + (size_t)(k - D) * D + n];
    ushort hi = f2bf(v);
    float  lo = v - bf2f(hi);
    Wh[i] = hi;
    Wl[i] = f2bf(lo);
}

// ---------------- x f32 -> hi/lo bf16 planes (pad rows zeroed) ----------------
__global__ __launch_bounds__(256)
void cvt_x_kernel(const float* __restrict__ x, ushort* __restrict__ xh,
                  ushort* __restrict__ xl) {
    size_t base = ((size_t)blockIdx.x * 256 + threadIdx.x) * 8;
    if (base >= (size_t)MPAD * D) return;
    ushort h[8], l[8];
    if (base < (size_t)NNODES * D) {
        float4 v0 = *reinterpret_cast<const float4*>(x + base);
        float4 v1 = *reinterpret_cast<const float4*>(x + base + 4);
        float vv[8] = {v0.x, v0.y, v0.z, v0.w, v1.x, v1.y, v1.z, v1.w};
#pragma unroll
        for (int j = 0; j < 8; ++j) {
            h[j] = f2bf(vv[j]);
            l[j] = f2bf(vv[j] - bf2f(h[j]));
        }
    } else {
#pragma unroll
        for (int j = 0; j < 8; ++j) { h[j] = 0; l[j] = 0; }
    }
    *reinterpret_cast<uint4*>(xh + base) = *reinterpret_cast<uint4*>(h);
    *reinterpret_cast<uint4*>(xl + base) = *reinterpret_cast<uint4*>(l);
}

// ---------------- gather-sum over hi/lo planes, writes hi/lo planes ----------------
__global__ __launch_bounds__(256)
void gather_hl_kernel(const ushort* __restrict__ ph, const ushort* __restrict__ pl,
                      const int* __restrict__ row_start, const int* __restrict__ e_src,
                      ushort* __restrict__ gh, ushort* __restrict__ gl) {
    int t = threadIdx.x;
    int n = blockIdx.x * 4 + (t >> 6);
    if (n >= NNODES) return;
    int lane = t & 63;
    int beg = row_start[n], end = row_start[n + 1];
    float a0 = 0.f, a1 = 0.f, a2 = 0.f, a3 = 0.f;
    int j = beg;
    for (; j + 4 <= end; j += 4) {
        int s0 = e_src[j], s1 = e_src[j + 1], s2 = e_src[j + 2], s3 = e_src[j + 3];
        ushort4 h0 = *reinterpret_cast<const ushort4*>(ph + (size_t)s0 * D + lane * 4);
        ushort4 l0 = *reinterpret_cast<const ushort4*>(pl + (size_t)s0 * D + lane * 4);
        ushort4 h1 = *reinterpret_cast<const ushort4*>(ph + (size_t)s1 * D + lane * 4);
        ushort4 l1 = *reinterpret_cast<const ushort4*>(pl + (size_t)s1 * D + lane * 4);
        ushort4 h2 = *reinterpret_cast<const ushort4*>(ph + (size_t)s2 * D + lane * 4);
        ushort4 l2 = *reinterpret_cast<const ushort4*>(pl + (size_t)s2 * D + lane * 4);
        ushort4 h3 = *reinterpret_cast<const ushort4*>(ph + (size_t)s3 * D + lane * 4);
        ushort4 l3 = *reinterpret_cast<const ushort4*>(pl + (size_t)s3 * D + lane * 4);
        a0 += (bf2f(h0.x) + bf2f(l0.x)) + (bf2f(h1.x) + bf2f(l1.x)) +
              (bf2f(h2.x) + bf2f(l2.x)) + (bf2f(h3.x) + bf2f(l3.x));
        a1 += (bf2f(h0.y) + bf2f(l0.y)) + (bf2f(h1.y) + bf2f(l1.y)) +
              (bf2f(h2.y) + bf2f(l2.y)) + (bf2f(h3.y) + bf2f(l3.y));
        a2 += (bf2f(h0.z) + bf2f(l0.z)) + (bf2f(h1.z) + bf2f(l1.z)) +
              (bf2f(h2.z) + bf2f(l2.z)) + (bf2f(h3.z) + bf2f(l3.z));
        a3 += (bf2f(h0.w) + bf2f(l0.w)) + (bf2f(h1.w) + bf2f(l1.w)) +
              (bf2f(h2.w) + bf2f(l2.w)) + (bf2f(h3.w) + bf2f(l3.w));
    }
    for (; j < end; ++j) {
        int s = e_src[j];
        ushort4 h = *reinterpret_cast<const ushort4*>(ph + (size_t)s * D + lane * 4);
        ushort4 l = *reinterpret_cast<const ushort4*>(pl + (size_t)s * D + lane * 4);
        a0 += bf2f(h.x) + bf2f(l.x);
        a1 += bf2f(h.y) + bf2f(l.y);
        a2 += bf2f(h.z) + bf2f(l.z);
        a3 += bf2f(h.w) + bf2f(l.w);
    }
    ushort4 oh, ol;
    oh.x = f2bf(a0); ol.x = f2bf(a0 - bf2f(oh.x));
    oh.y = f2bf(a1); ol.y = f2bf(a1 - bf2f(oh.y));
    oh.z = f2bf(a2); ol.z = f2bf(a2 - bf2f(oh.z));
    oh.w = f2bf(a3); ol.w = f2bf(a3 - bf2f(oh.w));
    *reinterpret_cast<ushort4*>(gh + (size_t)n * D + lane * 4) = oh;
    *reinterpret_cast<ushort4*>(gl + (size_t)n * D + lane * 4) = ol;
}

// ---------------- split-bf16 MFMA GEMM ----------------
// A: direct global->reg, double-buffered one K-step ahead.
// B: 3-buffer LDS via global_load_lds, counted vmcnt (never drained mid-loop).
#define GBM 128
#define GBN 128
#define GBK 32
#define NKS (K2 / GBK)   // 16

__global__ __launch_bounds__(256, 3)
void gemm_hl_kernel(const ushort* __restrict__ Gh, const ushort* __restrict__ Gl,
                    const ushort* __restrict__ Xh, const ushort* __restrict__ Xl,
                    const ushort* __restrict__ Wh, const ushort* __restrict__ Wl,
                    const float* __restrict__ bias,
                    ushort* __restrict__ outh, ushort* __restrict__ outl) {
    __shared__ ushort B_s[3][2][GBN * GBK];   // 48 KB -> 3 blocks/CU

    int t = threadIdx.x;
    int wid = t >> 6, lane = t & 63;
    int m0 = blockIdx.x * GBM;
    int n0 = blockIdx.y * GBN;
    int wr = wid >> 1, wc = wid & 1;
    int r = lane & 15, kq = lane >> 4;     // fragment coords

    f32x4 acc[4][4];
#pragma unroll
    for (int m = 0; m < 4; ++m)
#pragma unroll
        for (int n = 0; n < 4; ++n)
            acc[m][n] = (f32x4){0.f, 0.f, 0.f, 0.f};

    // B staging geometry (pre-swizzled source)
    int idxA = wid * 64 + lane;
    int idxB = 256 + idxA;
    int rowA = idxA >> 2, khA = ((rowA >> 1) & 3) ^ (idxA & 3);
    int rowB = idxB >> 2, khB = ((rowB >> 1) & 3) ^ (idxB & 3);
    size_t loA = (size_t)idxA * 8;
    size_t loB = (size_t)idxB * 8;

    // A-fragment register double buffer (static-indexed under full unroll)
    bf16x8 pah[2][4], pal[2][4];

    // prologue: stage B[0], B[1]; load A[0] into set 0
    stage16(Wh + (size_t)(n0 + rowA) * K2 + 0 + khA * 8, &B_s[0][0][loA]);
    stage16(Wh + (size_t)(n0 + rowB) * K2 + 0 + khB * 8, &B_s[0][0][loB]);
    stage16(Wl + (size_t)(n0 + rowA) * K2 + 0 + khA * 8, &B_s[0][1][loA]);
    stage16(Wl + (size_t)(n0 + rowB) * K2 + 0 + khB * 8, &B_s[0][1][loB]);
    stage16(Wh + (size_t)(n0 + rowA) * K2 + GBK + khA * 8, &B_s[1][0][loA]);
    stage16(Wh + (size_t)(n0 + rowB) * K2 + GBK + khB * 8, &B_s[1][0][loB]);
    stage16(Wl + (size_t)(n0 + rowA) * K2 + GBK + khA * 8, &B_s[1][1][loA]);
    stage16(Wl + (size_t)(n0 + rowB) * K2 + GBK + khB * 8, &B_s[1][1][loB]);
#pragma unroll
    for (int m = 0; m < 4; ++m) {
        size_t o = (size_t)(m0 + wr * 64 + m * 16 + r) * D + kq * 8;
        pah[0][m] = *reinterpret_cast<const bf16x8*>(Gh + o);
        pal[0][m] = *reinterpret_cast<const bf16x8*>(Gl + o);
    }

#pragma unroll
    for (int ks = 0; ks < NKS; ++ks) {
        // publish B[ks]: wait own stages done (counted — newer ops stay in flight),
        // then barrier so all waves see it. lgkmcnt(0): B[ks-1] reads retired.
        if (ks == 0)            asm volatile("s_waitcnt vmcnt(12) lgkmcnt(0)" ::: "memory");
        else if (ks == NKS - 1) asm volatile("s_waitcnt vmcnt(16) lgkmcnt(0)" ::: "memory");
        else                    asm volatile("s_waitcnt vmcnt(20) lgkmcnt(0)" ::: "memory");
        __builtin_amdgcn_s_barrier();
        __builtin_amdgcn_sched_barrier(0);

        // stage B[ks+2] into buf (ks+2)%3
        if (ks + 2 < NKS) {
            int kn = (ks + 2) * GBK;
            int bn = (ks + 2) % 3;
            stage16(Wh + (size_t)(n0 + rowA) * K2 + kn + khA * 8, &B_s[bn][0][loA]);
            stage16(Wh + (size_t)(n0 + rowB) * K2 + kn + khB * 8, &B_s[bn][0][loB]);
            stage16(Wl + (size_t)(n0 + rowA) * K2 + kn + khA * 8, &B_s[bn][1][loA]);
            stage16(Wl + (size_t)(n0 + rowB) * K2 + kn + khB * 8, &B_s[bn][1][loB]);
        }

        // prefetch A[ks+1] fragments into alternate register set
        if (ks + 1 < NKS) {
            int k1 = (ks + 1) * GBK;
            const ushort* ph = (k1 < D) ? Gh : Xh;
            const ushort* pl = (k1 < D) ? Gl : Xl;
            int kk1 = k1 & (D - 1);
            int s = (ks + 1) & 1;
#pragma unroll
            for (int m = 0; m < 4; ++m) {
                size_t o = (size_t)(m0 + wr * 64 + m * 16 + r) * D + kk1 + kq * 8;
                pah[s][m] = *reinterpret_cast<const bf16x8*>(ph + o);
                pal[s][m] = *reinterpret_cast<const bf16x8*>(pl + o);
            }
        }

        // compute with A[ks] (prefetched) and B[ks] (LDS buf ks%3)
        int cb = ks % 3;
        int cs = ks & 1;
#pragma unroll
        for (int n = 0; n < 4; ++n) {
            int rw = wc * 64 + n * 16 + r;
            int off = rw * GBK + ((((rw >> 1) & 3) ^ kq) * 8);
            bf16x8 bh = *reinterpret_cast<const bf16x8*>(&B_s[cb][0][off]);
            bf16x8 bl = *reinterpret_cast<const bf16x8*>(&B_s[cb][1][off]);
#pragma unroll
            for (int m = 0; m < 4; ++m) {
                acc[m][n] = __builtin_amdgcn_mfma_f32_16x16x32_bf16(pah[cs][m], bh, acc[m][n], 0, 0, 0);
                acc[m][n] = __builtin_amdgcn_mfma_f32_16x16x32_bf16(pah[cs][m], bl, acc[m][n], 0, 0, 0);
                acc[m][n] = __builtin_amdgcn_mfma_f32_16x16x32_bf16(pal[cs][m], bh, acc[m][n], 0, 0, 0);
            }
        }
    }

    // epilogue: bias + relu -> hi/lo bf16 planes
#pragma unroll
    for (int n = 0; n < 4; ++n) {
        int col = n0 + wc * 64 + n * 16 + r;
        float bv = bias[col];
#pragma unroll
        for (int m = 0; m < 4; ++m) {
            int rbase = m0 + wr * 64 + m * 16 + kq * 4;
#pragma unroll
            for (int j = 0; j < 4; ++j) {
                int rr = rbase + j;
                if (rr < NNODES) {
                    float v = fmaxf(acc[m][n][j] + bv, 0.f);
                    ushort hv = f2bf(v);
                    outh[(size_t)rr * D + col] = hv;
                    outl[(size_t)rr * D + col] = f2bf(v - bf2f(hv));
                }
            }
        }
    }
}

// ---------------- segmented pool over hi/lo planes (f32 out) ----------------
__global__ __launch_bounds__(256)
void pool_seg_kernel(const ushort* __restrict__ ph, const ushort* __restrict__ pl,
                     const int* __restrict__ gstart, float* __restrict__ pooled) {
    __shared__ float red[4][D];
    int g = blockIdx.x;
    int t = threadIdx.x, wid = t >> 6, lane = t & 63;
    int beg = gstart[g], end = gstart[g + 1];
    float a0 = 0.f, a1 = 0.f, a2 = 0.f, a3 = 0.f;
    for (int rr = beg + wid; rr < end; rr += 4) {
        ushort4 h = *reinterpret_cast<const ushort4*>(ph + (size_t)rr * D + lane * 4);
        ushort4 l = *reinterpret_cast<const ushort4*>(pl + (size_t)rr * D + lane * 4);
        a0 += bf2f(h.x) + bf2f(l.x);
        a1 += bf2f(h.y) + bf2f(l.y);
        a2 += bf2f(h.z) + bf2f(l.z);
        a3 += bf2f(h.w) + bf2f(l.w);
    }
    red[wid][lane * 4 + 0] = a0;
    red[wid][lane * 4 + 1] = a1;
    red[wid][lane * 4 + 2] = a2;
    red[wid][lane * 4 + 3] = a3;
    __syncthreads();
    float s = red[0][t] + red[1][t] + red[2][t] + red[3][t];
    pooled[(size_t)g * D + t] = s;
}

// ---------------- MLP layer 1 (f32) ----------------
__global__ __launch_bounds__(256)
void mlp1_kernel(const float* __restrict__ pooled, const float* __restrict__ W1,
                 const float* __restrict__ b1, float* __restrict__ h) {
    __shared__ float p[D];
    int g = blockIdx.x, t = threadIdx.x;
    p[t] = pooled[(size_t)g * D + t];
    __syncthreads();
    float4 acc = make_float4(0.f, 0.f, 0.f, 0.f);
    for (int k = 0; k < D; ++k) {
        float4 w = *reinterpret_cast<const float4*>(W1 + (size_t)k * 1024 + t * 4);
        float pv = p[k];
        acc.x += pv * w.x; acc.y += pv * w.y; acc.z += pv * w.z; acc.w += pv * w.w;
    }
    float4 b = *reinterpret_cast<const float4*>(b1 + t * 4);
    acc.x = fmaxf(acc.x + b.x, 0.f);
    acc.y = fmaxf(acc.y + b.y, 0.f);
    acc.z = fmaxf(acc.z + b.z, 0.f);
    acc.w = fmaxf(acc.w + b.w, 0.f);
    *reinterpret_cast<float4*>(h + (size_t)g * 1024 + t * 4) = acc;
}

// ---------------- MLP layer 2 (f32) ----------------
__global__ __launch_bounds__(256)
void mlp2_kernel(const float* __restrict__ h, const float* __restrict__ W2,
                 const float* __restrict__ b2, float* __restrict__ out) {
    __shared__ float red[8][32];
    int g = blockIdx.x, t = threadIdx.x;
    int c = t & 31, kc = t >> 5;
    float s = 0.f;
    const float* hr = h + (size_t)g * 1024;
    for (int k = kc * 128; k < kc * 128 + 128; ++k)
        s += hr[k] * W2[(size_t)k * 32 + c];
    red[kc][c] = s;
    __syncthreads();
    if (t < 32) {
        float v = b2[t];
#pragma unroll
        for (int i = 0; i < 8; ++i) v += red[i][t];
        out[(size_t)g * 32 + t] = 1.f / (1.f + expf(-v));
    }
}

extern "C" void kernel_launch(void* const* d_in, const int* in_sizes, int n_in,
                              void* d_out, int out_size, void* d_ws, size_t ws_size,
                              hipStream_t stream) {
    const float* x      = (const float*)d_in[0];
    const int*   ei     = (const int*)d_in[1];
    const int*   batch  = (const int*)d_in[2];
    const float* W_rel  = (const float*)d_in[3];
    const float* W_root = (const float*)d_in[4];
    const float* b_conv = (const float*)d_in[5];
    const float* W1     = (const float*)d_in[6];
    const float* b1     = (const float*)d_in[7];
    const float* W2     = (const float*)d_in[8];
    const float* b2     = (const float*)d_in[9];
    float* outp = (float*)d_out;

    const size_t NF = (size_t)MPAD * D;
    ushort* xh = (ushort*)d_ws;
    ushort* xl = xh + NF;
    ushort* yh = xl + NF;
    ushort* yl = yh + NF;
    ushort* gh = yl + NF;
    ushort* gl = gh + NF;
    ushort* Wh = gl + NF;                    // 3*256*512 each
    ushort* Wl = Wh + (size_t)NLAYERS * D * K2;
    float* pooled = (float*)(Wl + (size_t)NLAYERS * D * K2);
    float* hbuf   = pooled + (size_t)NGRAPH * D;
    int* deg       = (int*)(hbuf + (size_t)NGRAPH * 1024);
    int* row_start = deg + NNODES;           // NNODES+1
    int* cursor    = row_start + NNODES + 1;
    int* e_src     = cursor + NNODES;        // NEDGES
    int* gstart    = e_src + NEDGES;         // NGRAPH+1
    int* bsum      = gstart + NGRAPH + 1;    // NSCB
    int* boff      = bsum + NSCB;            // NSCB

    const int* srcp = ei;
    const int* dstp = ei + NEDGES;

    // CSR build (reused by all layers)
    hipMemsetAsync(deg, 0, NNODES * sizeof(int), stream);
    hist_kernel<<<(NEDGES + 255) / 256, 256, 0, stream>>>(dstp, deg, NEDGES);
    scan_part_kernel<<<NSCB, SCB, 0, stream>>>(deg, bsum);
    scan_bsum_kernel<<<1, 256, 0, stream>>>(bsum, boff);
    scan_final_kernel<<<NSCB, SCB, 0, stream>>>(deg, boff, row_start, cursor);
    fill_kernel<<<(NEDGES + 255) / 256, 256, 0, stream>>>(srcp, dstp, cursor, e_src, NEDGES);
    gstart_kernel<<<3, 256, 0, stream>>>(batch, gstart);

    prep_w_kernel<<<(NLAYERS * D * K2 + 255) / 256, 256, 0, stream>>>(W_rel, W_root, Wh, Wl);
    cvt_x_kernel<<<(int)((NF / 8 + 255) / 256), 256, 0, stream>>>(x, xh, xl);

    int gatherBlocks = (NNODES + 3) / 4;
    dim3 ggrid(MPAD / GBM, D / GBN);

    const ushort* curh = xh; const ushort* curl = xl;
    ushort* nxth = yh;       ushort* nxtl = yl;
    for (int L = 0; L < NLAYERS; ++L) {
        gather_hl_kernel<<<gatherBlocks, 256, 0, stream>>>(curh, curl, row_start, e_src, gh, gl);
        gemm_hl_kernel<<<ggrid, 256, 0, stream>>>(gh, gl, curh, curl,
                                                  Wh + (size_t)L * D * K2,
                                                  Wl + (size_t)L * D * K2,
                                                  b_conv + (size_t)L * D,
                                                  nxth, nxtl);
        // swap P-pair roles
        const ushort* th = curh; const ushort* tl = curl;
        curh = nxth; curl = nxtl;
        nxth = (ushort*)th; nxtl = (ushort*)tl;
        if (L == 0) { nxth = xh; nxtl = xl; }   // after L0: cur=P1, next writes into P0
    }

    pool_seg_kernel<<<NGRAPH, 256, 0, stream>>>(curh, curl, gstart, pooled);
    mlp1_kernel<<<NGRAPH, 256, 0, stream>>>(pooled, W1, b1, hbuf);
    mlp2_kernel<<<NGRAPH, 256, 0, stream>>>(hbuf, W2, b2, outp);
}

// Round 11
// 490.009 us; speedup vs baseline: 1.1565x; 1.1115x over previous
//
#include <hip/hip_runtime.h>
#include <math.h>

#define NNODES 50000
#define MPAD   50048    // NNODES rounded up to 128
#define D      256
#define K2     512
#define NEDGES 300000
#define NGRAPH 512
#define NLAYERS 3

#define SCB    256
#define NSCB   ((NNODES + SCB - 1) / SCB)   // 196 blocks

typedef __bf16 bf16x8 __attribute__((ext_vector_type(8)));
typedef float  f32x4  __attribute__((ext_vector_type(4)));

__device__ __forceinline__ ushort f2bf(float f) {
    unsigned u = __float_as_uint(f);
    unsigned r = (u + 0x7FFFu + ((u >> 16) & 1u)) >> 16;   // RNE
    return (ushort)r;
}
__device__ __forceinline__ float bf2f(ushort b) {
    return __uint_as_float(((unsigned)b) << 16);
}

__device__ __forceinline__ void stage16(const ushort* g, ushort* l) {
    __builtin_amdgcn_global_load_lds(
        (const __attribute__((address_space(1))) unsigned*)g,
        (__attribute__((address_space(3))) unsigned*)l, 16, 0, 0);
}

// ---------------- CSR build ----------------
__global__ __launch_bounds__(256)
void hist_kernel(const int* __restrict__ dst, int* __restrict__ deg, int nE) {
    int e = blockIdx.x * 256 + threadIdx.x;
    if (e < nE) atomicAdd(&deg[dst[e]], 1);
}

__global__ __launch_bounds__(SCB)
void scan_part_kernel(const int* __restrict__ deg, int* __restrict__ bsum) {
    __shared__ int red[SCB];
    int t = threadIdx.x;
    int i = blockIdx.x * SCB + t;
    red[t] = (i < NNODES) ? deg[i] : 0;
    __syncthreads();
#pragma unroll
    for (int off = SCB / 2; off > 0; off >>= 1) {
        if (t < off) red[t] += red[t + off];
        __syncthreads();
    }
    if (t == 0) bsum[blockIdx.x] = red[0];
}

__global__ __launch_bounds__(256)
void scan_bsum_kernel(const int* __restrict__ bsum, int* __restrict__ boff) {
    __shared__ int p[256];
    int t = threadIdx.x;
    p[t] = (t < NSCB) ? bsum[t] : 0;
    __syncthreads();
    for (int off = 1; off < 256; off <<= 1) {
        int v = (t >= off) ? p[t - off] : 0;
        __syncthreads();
        p[t] += v;
        __syncthreads();
    }
    if (t < NSCB) boff[t] = (t == 0) ? 0 : p[t - 1];
}

__global__ __launch_bounds__(SCB)
void scan_final_kernel(const int* __restrict__ deg, const int* __restrict__ boff,
                       int* __restrict__ row_start, int* __restrict__ cursor) {
    __shared__ int p[SCB];
    int t = threadIdx.x;
    int i = blockIdx.x * SCB + t;
    int v = (i < NNODES) ? deg[i] : 0;
    p[t] = v;
    __syncthreads();
    for (int off = 1; off < SCB; off <<= 1) {
        int u = (t >= off) ? p[t - off] : 0;
        __syncthreads();
        p[t] += u;
        __syncthreads();
    }
    int excl = boff[blockIdx.x] + p[t] - v;
    if (i < NNODES) {
        row_start[i] = excl;
        cursor[i] = excl;
    }
    if (blockIdx.x == 0 && t == 0) row_start[NNODES] = NEDGES;
}

__global__ __launch_bounds__(256)
void fill_kernel(const int* __restrict__ src, const int* __restrict__ dst,
                 int* __restrict__ cursor, int* __restrict__ e_src, int nE) {
    int e = blockIdx.x * 256 + threadIdx.x;
    if (e < nE) {
        int pos = atomicAdd(&cursor[dst[e]], 1);
        e_src[pos] = src[e];
    }
}

// ---------------- graph segment starts (batch sorted) ----------------
__global__ __launch_bounds__(256)
void gstart_kernel(const int* __restrict__ batch, int* __restrict__ gstart) {
    int g = blockIdx.x * 256 + threadIdx.x;
    if (g > NGRAPH) return;
    if (g == NGRAPH) { gstart[g] = NNODES; return; }
    int lo = 0, hi = NNODES;
    while (lo < hi) { int mid = (lo + hi) >> 1; if (batch[mid] < g) lo = mid + 1; else hi = mid; }
    gstart[g] = lo;
}

// ---------------- weight prep: split into hi/lo bf16, [L][n][k] ----------------
__global__ __launch_bounds__(256)
void prep_w_kernel(const float* __restrict__ W_rel, const float* __restrict__ W_root,
                   ushort* __restrict__ Wh, ushort* __restrict__ Wl) {
    int i = blockIdx.x * 256 + threadIdx.x;
    if (i >= NLAYERS * D * K2) return;
    int L = i / (D * K2);
    int rem = i % (D * K2);
    int n = rem / K2;
    int k = rem % K2;
    float v = (k < D) ? W_rel[(size_t)L * D * D + (size_t)k * D + n]
                      : W_root[(size_t)L * D * D + (size_t)(k - D) * D + n];
    ushort hi = f2bf(v);
    float  lo = v - bf2f(hi);
    Wh[i] = hi;
    Wl[i] = f2bf(lo);
}

// ---------------- x f32 -> hi/lo bf16 planes (pad rows zeroed) ----------------
__global__ __launch_bounds__(256)
void cvt_x_kernel(const float* __restrict__ x, ushort* __restrict__ xh,
                  ushort* __restrict__ xl) {
    size_t base = ((size_t)blockIdx.x * 256 + threadIdx.x) * 8;
    if (base >= (size_t)MPAD * D) return;
    ushort h[8], l[8];
    if (base < (size_t)NNODES * D) {
        float4 v0 = *reinterpret_cast<const float4*>(x + base);
        float4 v1 = *reinterpret_cast<const float4*>(x + base + 4);
        float vv[8] = {v0.x, v0.y, v0.z, v0.w, v1.x, v1.y, v1.z, v1.w};
#pragma unroll
        for (int j = 0; j < 8; ++j) {
            h[j] = f2bf(vv[j]);
            l[j] = f2bf(vv[j] - bf2f(h[j]));
        }
    } else {
#pragma unroll
        for (int j = 0; j < 8; ++j) { h[j] = 0; l[j] = 0; }
    }
    *reinterpret_cast<uint4*>(xh + base) = *reinterpret_cast<uint4*>(h);
    *reinterpret_cast<uint4*>(xl + base) = *reinterpret_cast<uint4*>(l);
}

// ---------------- gather-sum over hi/lo planes, writes hi/lo planes ----------------
__global__ __launch_bounds__(256)
void gather_hl_kernel(const ushort* __restrict__ ph, const ushort* __restrict__ pl,
                      const int* __restrict__ row_start, const int* __restrict__ e_src,
                      ushort* __restrict__ gh, ushort* __restrict__ gl) {
    int t = threadIdx.x;
    int n = blockIdx.x * 4 + (t >> 6);
    if (n >= NNODES) return;
    int lane = t & 63;
    int beg = row_start[n], end = row_start[n + 1];
    float a0 = 0.f, a1 = 0.f, a2 = 0.f, a3 = 0.f;
    int j = beg;
    for (; j + 4 <= end; j += 4) {
        int s0 = e_src[j], s1 = e_src[j + 1], s2 = e_src[j + 2], s3 = e_src[j + 3];
        ushort4 h0 = *reinterpret_cast<const ushort4*>(ph + (size_t)s0 * D + lane * 4);
        ushort4 l0 = *reinterpret_cast<const ushort4*>(pl + (size_t)s0 * D + lane * 4);
        ushort4 h1 = *reinterpret_cast<const ushort4*>(ph + (size_t)s1 * D + lane * 4);
        ushort4 l1 = *reinterpret_cast<const ushort4*>(pl + (size_t)s1 * D + lane * 4);
        ushort4 h2 = *reinterpret_cast<const ushort4*>(ph + (size_t)s2 * D + lane * 4);
        ushort4 l2 = *reinterpret_cast<const ushort4*>(pl + (size_t)s2 * D + lane * 4);
        ushort4 h3 = *reinterpret_cast<const ushort4*>(ph + (size_t)s3 * D + lane * 4);
        ushort4 l3 = *reinterpret_cast<const ushort4*>(pl + (size_t)s3 * D + lane * 4);
        a0 += (bf2f(h0.x) + bf2f(l0.x)) + (bf2f(h1.x) + bf2f(l1.x)) +
              (bf2f(h2.x) + bf2f(l2.x)) + (bf2f(h3.x) + bf2f(l3.x));
        a1 += (bf2f(h0.y) + bf2f(l0.y)) + (bf2f(h1.y) + bf2f(l1.y)) +
              (bf2f(h2.y) + bf2f(l2.y)) + (bf2f(h3.y) + bf2f(l3.y));
        a2 += (bf2f(h0.z) + bf2f(l0.z)) + (bf2f(h1.z) + bf2f(l1.z)) +
              (bf2f(h2.z) + bf2f(l2.z)) + (bf2f(h3.z) + bf2f(l3.z));
        a3 += (bf2f(h0.w) + bf2f(l0.w)) + (bf2f(h1.w) + bf2f(l1.w)) +
              (bf2f(h2.w) + bf2f(l2.w)) + (bf2f(h3.w) + bf2f(l3.w));
    }
    for (; j < end; ++j) {
        int s = e_src[j];
        ushort4 h = *reinterpret_cast<const ushort4*>(ph + (size_t)s * D + lane * 4);
        ushort4 l = *reinterpret_cast<const ushort4*>(pl + (size_t)s * D + lane * 4);
        a0 += bf2f(h.x) + bf2f(l.x);
        a1 += bf2f(h.y) + bf2f(l.y);
        a2 += bf2f(h.z) + bf2f(l.z);
        a3 += bf2f(h.w) + bf2f(l.w);
    }
    ushort4 oh, ol;
    oh.x = f2bf(a0); ol.x = f2bf(a0 - bf2f(oh.x));
    oh.y = f2bf(a1); ol.y = f2bf(a1 - bf2f(oh.y));
    oh.z = f2bf(a2); ol.z = f2bf(a2 - bf2f(oh.z));
    oh.w = f2bf(a3); ol.w = f2bf(a3 - bf2f(oh.w));
    *reinterpret_cast<ushort4*>(gh + (size_t)n * D + lane * 4) = oh;
    *reinterpret_cast<ushort4*>(gl + (size_t)n * D + lane * 4) = ol;
}

// ---------------- split-bf16 MFMA GEMM: 3-buffer LDS, 1 raw barrier/step, counted vmcnt ----------------
// out = relu([G|X] @ W^T + bias); all operands hi/lo bf16 plane pairs.
// NO plain VMEM loads in the K-loop: every operand byte moves via global_load_lds,
// so the only vmcnt waits are the hand-counted ones below.
#define GBM 128
#define GBN 128
#define GBK 32
#define NKS (K2 / GBK)   // 16

__global__ __launch_bounds__(512)
void gemm_hl_kernel(const ushort* __restrict__ Gh, const ushort* __restrict__ Gl,
                    const ushort* __restrict__ Xh, const ushort* __restrict__ Xl,
                    const ushort* __restrict__ Wh, const ushort* __restrict__ Wl,
                    const float* __restrict__ bias,
                    ushort* __restrict__ outh, ushort* __restrict__ outl) {
    // 3 buffers x 4 planes (Ah,Al,Bh,Bl) x 8 KB = 96 KB -> 1 block (8 waves) per CU
    __shared__ ushort S[3][4][GBM * GBK];

    int t = threadIdx.x;
    int wid = t >> 6, lane = t & 63;
    int m0 = blockIdx.x * GBM;
    int n0 = blockIdx.y * GBN;
    int wr = wid >> 1, wc = wid & 1;       // 4x2 wave grid: per wave 32 rows x 64 cols
    int r = lane & 15, kq = lane >> 4;

    f32x4 acc[2][4];
#pragma unroll
    for (int m = 0; m < 2; ++m)
#pragma unroll
        for (int n = 0; n < 4; ++n)
            acc[m][n] = (f32x4){0.f, 0.f, 0.f, 0.f};

    // staging: thread t stages chunk t (of 512) of each plane; 4 stage16/thread/step
    // pre-swizzled source: physical chunk sub holds k-half ((row>>1)&3)^sub
    int srow = t >> 2, ssub = t & 3;
    int skh = ((srow >> 1) & 3) ^ ssub;
    size_t slo = (size_t)t * 8;            // elem offset within a plane

#define STAGE(ksx)                                                                  \
    {                                                                               \
        int k0_ = (ksx) * GBK;                                                      \
        const ushort* ah_ = (k0_ < D) ? Gh : Xh;                                    \
        const ushort* al_ = (k0_ < D) ? Gl : Xl;                                    \
        int kk_ = k0_ & (D - 1);                                                    \
        int b_ = (ksx) % 3;                                                         \
        stage16(ah_ + (size_t)(m0 + srow) * D + kk_ + skh * 8, &S[b_][0][slo]);     \
        stage16(al_ + (size_t)(m0 + srow) * D + kk_ + skh * 8, &S[b_][1][slo]);     \
        stage16(Wh + (size_t)(n0 + srow) * K2 + k0_ + skh * 8, &S[b_][2][slo]);     \
        stage16(Wl + (size_t)(n0 + srow) * K2 + k0_ + skh * 8, &S[b_][3][slo]);     \
    }

    // prologue: 2-deep prefetch
    STAGE(0);
    STAGE(1);

    for (int ks = 0; ks < NKS; ++ks) {
        // Counted wait: retire S[ks]'s 4 stages; S[ks+1]'s 4 stay in flight.
        if (ks < NKS - 1) asm volatile("s_waitcnt vmcnt(4)" ::: "memory");
        else              asm volatile("s_waitcnt vmcnt(0)" ::: "memory");
        __builtin_amdgcn_s_barrier();          // publish S[ks] to all waves
        __builtin_amdgcn_sched_barrier(0);

        // issue S[ks+2] into buf (ks+2)%3 == (ks-1)%3: its readers (step ks-1)
        // all retired before the barrier above -> no reuse hazard.
        if (ks + 2 < NKS) STAGE(ks + 2);

        int cb = ks % 3;
        bf16x8 fah[2], fal[2], fbh[4], fbl[4];
#pragma unroll
        for (int m = 0; m < 2; ++m) {
            int rw = wr * 32 + m * 16 + r;
            int off = rw * GBK + ((((rw >> 1) & 3) ^ kq) * 8);
            fah[m] = *reinterpret_cast<const bf16x8*>(&S[cb][0][off]);
            fal[m] = *reinterpret_cast<const bf16x8*>(&S[cb][1][off]);
        }
#pragma unroll
        for (int n = 0; n < 4; ++n) {
            int rw = wc * 64 + n * 16 + r;
            int off = rw * GBK + ((((rw >> 1) & 3) ^ kq) * 8);
            fbh[n] = *reinterpret_cast<const bf16x8*>(&S[cb][2][off]);
            fbl[n] = *reinterpret_cast<const bf16x8*>(&S[cb][3][off]);
        }
#pragma unroll
        for (int m = 0; m < 2; ++m)
#pragma unroll
            for (int n = 0; n < 4; ++n) {
                acc[m][n] = __builtin_amdgcn_mfma_f32_16x16x32_bf16(fah[m], fbh[n], acc[m][n], 0, 0, 0);
                acc[m][n] = __builtin_amdgcn_mfma_f32_16x16x32_bf16(fah[m], fbl[n], acc[m][n], 0, 0, 0);
                acc[m][n] = __builtin_amdgcn_mfma_f32_16x16x32_bf16(fal[m], fbh[n], acc[m][n], 0, 0, 0);
            }
        // no trailing barrier: next iteration's vmcnt+barrier provides it
    }
#undef STAGE

    // epilogue: bias + relu -> hi/lo bf16 planes
#pragma unroll
    for (int n = 0; n < 4; ++n) {
        int col = n0 + wc * 64 + n * 16 + r;
        float bv = bias[col];
#pragma unroll
        for (int m = 0; m < 2; ++m) {
            int rbase = m0 + wr * 32 + m * 16 + kq * 4;
#pragma unroll
            for (int j = 0; j < 4; ++j) {
                int rr = rbase + j;
                if (rr < NNODES) {
                    float v = fmaxf(acc[m][n][j] + bv, 0.f);
                    ushort hv = f2bf(v);
                    outh[(size_t)rr * D + col] = hv;
                    outl[(size_t)rr * D + col] = f2bf(v - bf2f(hv));
                }
            }
        }
    }
}

// ---------------- segmented pool over hi/lo planes (f32 out) ----------------
__global__ __launch_bounds__(256)
void pool_seg_kernel(const ushort* __restrict__ ph, const ushort* __restrict__ pl,
                     const int* __restrict__ gstart, float* __restrict__ pooled) {
    __shared__ float red[4][D];
    int g = blockIdx.x;
    int t = threadIdx.x, wid = t >> 6, lane = t & 63;
    int beg = gstart[g], end = gstart[g + 1];
    float a0 = 0.f, a1 = 0.f, a2 = 0.f, a3 = 0.f;
    for (int rr = beg + wid; rr < end; rr += 4) {
        ushort4 h = *reinterpret_cast<const ushort4*>(ph + (size_t)rr * D + lane * 4);
        ushort4 l = *reinterpret_cast<const ushort4*>(pl + (size_t)rr * D + lane * 4);
        a0 += bf2f(h.x) + bf2f(l.x);
        a1 += bf2f(h.y) + bf2f(l.y);
        a2 += bf2f(h.z) + bf2f(l.z);
        a3 += bf2f(h.w) + bf2f(l.w);
    }
    red[wid][lane * 4 + 0] = a0;
    red[wid][lane * 4 + 1] = a1;
    red[wid][lane * 4 + 2] = a2;
    red[wid][lane * 4 + 3] = a3;
    __syncthreads();
    float s = red[0][t] + red[1][t] + red[2][t] + red[3][t];
    pooled[(size_t)g * D + t] = s;
}

// ---------------- MLP layer 1 (f32) ----------------
__global__ __launch_bounds__(256)
void mlp1_kernel(const float* __restrict__ pooled, const float* __restrict__ W1,
                 const float* __restrict__ b1, float* __restrict__ h) {
    __shared__ float p[D];
    int g = blockIdx.x, t = threadIdx.x;
    p[t] = pooled[(size_t)g * D + t];
    __syncthreads();
    float4 acc = make_float4(0.f, 0.f, 0.f, 0.f);
    for (int k = 0; k < D; ++k) {
        float4 w = *reinterpret_cast<const float4*>(W1 + (size_t)k * 1024 + t * 4);
        float pv = p[k];
        acc.x += pv * w.x; acc.y += pv * w.y; acc.z += pv * w.z; acc.w += pv * w.w;
    }
    float4 b = *reinterpret_cast<const float4*>(b1 + t * 4);
    acc.x = fmaxf(acc.x + b.x, 0.f);
    acc.y = fmaxf(acc.y + b.y, 0.f);
    acc.z = fmaxf(acc.z + b.z, 0.f);
    acc.w = fmaxf(acc.w + b.w, 0.f);
    *reinterpret_cast<float4*>(h + (size_t)g * 1024 + t * 4) = acc;
}

// ---------------- MLP layer 2 (f32) ----------------
__global__ __launch_bounds__(256)
void mlp2_kernel(const float* __restrict__ h, const float* __restrict__ W2,
                 const float* __restrict__ b2, float* __restrict__ out) {
    __shared__ float red[8][32];
    int g = blockIdx.x, t = threadIdx.x;
    int c = t & 31, kc = t >> 5;
    float s = 0.f;
    const float* hr = h + (size_t)g * 1024;
    for (int k = kc * 128; k < kc * 128 + 128; ++k)
        s += hr[k] * W2[(size_t)k * 32 + c];
    red[kc][c] = s;
    __syncthreads();
    if (t < 32) {
        float v = b2[t];
#pragma unroll
        for (int i = 0; i < 8; ++i) v += red[i][t];
        out[(size_t)g * 32 + t] = 1.f / (1.f + expf(-v));
    }
}

extern "C" void kernel_launch(void* const* d_in, const int* in_sizes, int n_in,
                              void* d_out, int out_size, void* d_ws, size_t ws_size,
                              hipStream_t stream) {
    const float* x      = (const float*)d_in[0];
    const int*   ei     = (const int*)d_in[1];
    const int*   batch  = (const int*)d_in[2];
    const float* W_rel  = (const float*)d_in[3];
    const float* W_root = (const float*)d_in[4];
    const float* b_conv = (const float*)d_in[5];
    const float* W1     = (const float*)d_in[6];
    const float* b1     = (const float*)d_in[7];
    const float* W2     = (const float*)d_in[8];
    const float* b2     = (const float*)d_in[9];
    float* outp = (float*)d_out;

    const size_t NF = (size_t)MPAD * D;
    ushort* xh = (ushort*)d_ws;
    ushort* xl = xh + NF;
    ushort* yh = xl + NF;
    ushort* yl = yh + NF;
    ushort* gh = yl + NF;
    ushort* gl = gh + NF;
    ushort* Wh = gl + NF;                    // 3*256*512 each
    ushort* Wl = Wh + (size_t)NLAYERS * D * K2;
    float* pooled = (float*)(Wl + (size_t)NLAYERS * D * K2);
    float* hbuf   = pooled + (size_t)NGRAPH * D;
    int* deg       = (int*)(hbuf + (size_t)NGRAPH * 1024);
    int* row_start = deg + NNODES;           // NNODES+1
    int* cursor    = row_start + NNODES + 1;
    int* e_src     = cursor + NNODES;        // NEDGES
    int* gstart    = e_src + NEDGES;         // NGRAPH+1
    int* bsum      = gstart + NGRAPH + 1;    // NSCB
    int* boff      = bsum + NSCB;            // NSCB

    const int* srcp = ei;
    const int* dstp = ei + NEDGES;

    // CSR build (reused by all layers)
    hipMemsetAsync(deg, 0, NNODES * sizeof(int), stream);
    hist_kernel<<<(NEDGES + 255) / 256, 256, 0, stream>>>(dstp, deg, NEDGES);
    scan_part_kernel<<<NSCB, SCB, 0, stream>>>(deg, bsum);
    scan_bsum_kernel<<<1, 256, 0, stream>>>(bsum, boff);
    scan_final_kernel<<<NSCB, SCB, 0, stream>>>(deg, boff, row_start, cursor);
    fill_kernel<<<(NEDGES + 255) / 256, 256, 0, stream>>>(srcp, dstp, cursor, e_src, NEDGES);
    gstart_kernel<<<3, 256, 0, stream>>>(batch, gstart);

    prep_w_kernel<<<(NLAYERS * D * K2 + 255) / 256, 256, 0, stream>>>(W_rel, W_root, Wh, Wl);
    cvt_x_kernel<<<(int)((NF / 8 + 255) / 256), 256, 0, stream>>>(x, xh, xl);

    int gatherBlocks = (NNODES + 3) / 4;
    dim3 ggrid(MPAD / GBM, D / GBN);

    const ushort* curh = xh; const ushort* curl = xl;
    ushort* nxth = yh;       ushort* nxtl = yl;
    for (int L = 0; L < NLAYERS; ++L) {
        gather_hl_kernel<<<gatherBlocks, 256, 0, stream>>>(curh, curl, row_start, e_src, gh, gl);
        gemm_hl_kernel<<<ggrid, 512, 0, stream>>>(gh, gl, curh, curl,
                                                  Wh + (size_t)L * D * K2,
                                                  Wl + (size_t)L * D * K2,
                                                  b_conv + (size_t)L * D,
                                                  nxth, nxtl);
        // swap P-pair roles
        const ushort* th = curh; const ushort* tl = curl;
        curh = nxth; curl = nxtl;
        nxth = (ushort*)th; nxtl = (ushort*)tl;
        if (L == 0) { nxth = xh; nxtl = xl; }   // after L0: cur=P1, next writes into P0
    }

    pool_seg_kernel<<<NGRAPH, 256, 0, stream>>>(curh, curl, gstart, pooled);
    mlp1_kernel<<<NGRAPH, 256, 0, stream>>>(pooled, W1, b1, hbuf);
    mlp2_kernel<<<NGRAPH, 256, 0, stream>>>(hbuf, W2, b2, outp);
}

// Round 12
// 476.171 us; speedup vs baseline: 1.1901x; 1.0291x over previous
//
#include <hip/hip_runtime.h>
#include <math.h>

#define NNODES 50000
#define MPAD   50048    // NNODES rounded up to 128
#define D      256
#define K2     512
#define NEDGES 300000
#define NGRAPH 512
#define NLAYERS 3

#define SCB    256
#define NSCB   ((NNODES + SCB - 1) / SCB)   // 196 blocks

typedef __bf16 bf16x8 __attribute__((ext_vector_type(8)));
typedef float  f32x4  __attribute__((ext_vector_type(4)));

__device__ __forceinline__ ushort f2bf(float f) {
    unsigned u = __float_as_uint(f);
    unsigned r = (u + 0x7FFFu + ((u >> 16) & 1u)) >> 16;   // RNE
    return (ushort)r;
}
__device__ __forceinline__ float bf2f(ushort b) {
    return __uint_as_float(((unsigned)b) << 16);
}

__device__ __forceinline__ void stage16(const ushort* g, ushort* l) {
    __builtin_amdgcn_global_load_lds(
        (const __attribute__((address_space(1))) unsigned*)g,
        (__attribute__((address_space(3))) unsigned*)l, 16, 0, 0);
}

// ---------------- CSR build ----------------
__global__ __launch_bounds__(256)
void hist_kernel(const int* __restrict__ dst, int* __restrict__ deg, int nE) {
    int e = blockIdx.x * 256 + threadIdx.x;
    if (e < nE) atomicAdd(&deg[dst[e]], 1);
}

__global__ __launch_bounds__(SCB)
void scan_part_kernel(const int* __restrict__ deg, int* __restrict__ bsum) {
    __shared__ int red[SCB];
    int t = threadIdx.x;
    int i = blockIdx.x * SCB + t;
    red[t] = (i < NNODES) ? deg[i] : 0;
    __syncthreads();
#pragma unroll
    for (int off = SCB / 2; off > 0; off >>= 1) {
        if (t < off) red[t] += red[t + off];
        __syncthreads();
    }
    if (t == 0) bsum[blockIdx.x] = red[0];
}

__global__ __launch_bounds__(256)
void scan_bsum_kernel(const int* __restrict__ bsum, int* __restrict__ boff) {
    __shared__ int p[256];
    int t = threadIdx.x;
    p[t] = (t < NSCB) ? bsum[t] : 0;
    __syncthreads();
    for (int off = 1; off < 256; off <<= 1) {
        int v = (t >= off) ? p[t - off] : 0;
        __syncthreads();
        p[t] += v;
        __syncthreads();
    }
    if (t < NSCB) boff[t] = (t == 0) ? 0 : p[t - 1];
}

__global__ __launch_bounds__(SCB)
void scan_final_kernel(const int* __restrict__ deg, const int* __restrict__ boff,
                       int* __restrict__ row_start, int* __restrict__ cursor) {
    __shared__ int p[SCB];
    int t = threadIdx.x;
    int i = blockIdx.x * SCB + t;
    int v = (i < NNODES) ? deg[i] : 0;
    p[t] = v;
    __syncthreads();
    for (int off = 1; off < SCB; off <<= 1) {
        int u = (t >= off) ? p[t - off] : 0;
        __syncthreads();
        p[t] += u;
        __syncthreads();
    }
    int excl = boff[blockIdx.x] + p[t] - v;
    if (i < NNODES) {
        row_start[i] = excl;
        cursor[i] = excl;
    }
    if (blockIdx.x == 0 && t == 0) row_start[NNODES] = NEDGES;
}

__global__ __launch_bounds__(256)
void fill_kernel(const int* __restrict__ src, const int* __restrict__ dst,
                 int* __restrict__ cursor, int* __restrict__ e_src, int nE) {
    int e = blockIdx.x * 256 + threadIdx.x;
    if (e < nE) {
        int pos = atomicAdd(&cursor[dst[e]], 1);
        e_src[pos] = src[e];
    }
}

// ---------------- graph segment starts (batch sorted) ----------------
__global__ __launch_bounds__(256)
void gstart_kernel(const int* __restrict__ batch, int* __restrict__ gstart) {
    int g = blockIdx.x * 256 + threadIdx.x;
    if (g > NGRAPH) return;
    if (g == NGRAPH) { gstart[g] = NNODES; return; }
    int lo = 0, hi = NNODES;
    while (lo < hi) { int mid = (lo + hi) >> 1; if (batch[mid] < g) lo = mid + 1; else hi = mid; }
    gstart[g] = lo;
}

// ---------------- weight prep: split into hi/lo bf16, [L][n][k] ----------------
__global__ __launch_bounds__(256)
void prep_w_kernel(const float* __restrict__ W_rel, const float* __restrict__ W_root,
                   ushort* __restrict__ Wh, ushort* __restrict__ Wl) {
    int i = blockIdx.x * 256 + threadIdx.x;
    if (i >= NLAYERS * D * K2) return;
    int L = i / (D * K2);
    int rem = i % (D * K2);
    int n = rem / K2;
    int k = rem % K2;
    float v = (k < D) ? W_rel[(size_t)L * D * D + (size_t)k * D + n]
                      : W_root[(size_t)L * D * D + (size_t)(k - D) * D + n];
    ushort hi = f2bf(v);
    float  lo = v - bf2f(hi);
    Wh[i] = hi;
    Wl[i] = f2bf(lo);
}

// ---------------- f32 gather-sum with 4-wide index unroll ----------------
__global__ __launch_bounds__(256)
void gather_f32_kernel(const float* __restrict__ x,
                       const int* __restrict__ row_start,
                       const int* __restrict__ e_src,
                       float* __restrict__ aggr) {
    int t = threadIdx.x;
    int n = blockIdx.x * 4 + (t >> 6);
    if (n >= NNODES) return;
    int lane = t & 63;
    int beg = row_start[n], end = row_start[n + 1];
    float a0 = 0.f, a1 = 0.f, a2 = 0.f, a3 = 0.f;
    int j = beg;
    for (; j + 4 <= end; j += 4) {
        int s0 = e_src[j], s1 = e_src[j + 1], s2 = e_src[j + 2], s3 = e_src[j + 3];
        float4 v0 = *reinterpret_cast<const float4*>(x + (size_t)s0 * D + lane * 4);
        float4 v1 = *reinterpret_cast<const float4*>(x + (size_t)s1 * D + lane * 4);
        float4 v2 = *reinterpret_cast<const float4*>(x + (size_t)s2 * D + lane * 4);
        float4 v3 = *reinterpret_cast<const float4*>(x + (size_t)s3 * D + lane * 4);
        a0 += v0.x + v1.x + v2.x + v3.x;
        a1 += v0.y + v1.y + v2.y + v3.y;
        a2 += v0.z + v1.z + v2.z + v3.z;
        a3 += v0.w + v1.w + v2.w + v3.w;
    }
    for (; j < end; ++j) {
        int s = e_src[j];
        float4 v = *reinterpret_cast<const float4*>(x + (size_t)s * D + lane * 4);
        a0 += v.x; a1 += v.y; a2 += v.z; a3 += v.w;
    }
    float4 o; o.x = a0; o.y = a1; o.z = a2; o.w = a3;
    *reinterpret_cast<float4*>(aggr + (size_t)n * D + lane * 4) = o;
}

// ---------------- split-bf16 MFMA GEMM: out = relu([A|X]@W^T + bias), f32 in/out ----------------
// A,X: [MPAD][256] f32 (K-concat), Wh/Wl: [256 n][512 k] bf16, out: [MPAD][256] f32
#define GBM 128
#define GBN 128
#define GBK 32

__global__ __launch_bounds__(256)
void gemm_split_kernel(const float* __restrict__ A,
                       const float* __restrict__ X,
                       const ushort* __restrict__ Wh,
                       const ushort* __restrict__ Wl,
                       const float* __restrict__ bias,
                       float* __restrict__ out) {
    __shared__ ushort Ah[GBM * GBK];   // 8 KB each
    __shared__ ushort Al[GBM * GBK];
    __shared__ ushort Bh[GBN * GBK];
    __shared__ ushort Bl[GBN * GBK];

    int t = threadIdx.x;
    int wid = t >> 6, lane = t & 63;
    int m0 = blockIdx.x * GBM;
    int n0 = blockIdx.y * GBN;
    int wr = wid >> 1, wc = wid & 1;

    f32x4 acc[4][4];
#pragma unroll
    for (int m = 0; m < 4; ++m)
#pragma unroll
        for (int n = 0; n < 4; ++n)
            acc[m][n] = (f32x4){0.f, 0.f, 0.f, 0.f};

    // A staging coords: thread t owns row t>>1, 16 consecutive f32 at k-offset (t&1)*16
    int arow = t >> 1;
    int acb  = (t & 1) * 2;           // first 8-elem k-chunk owned
    int aswz = (arow >> 1) & 3;
    int gr   = m0 + arow;
    bool arow_ok = (gr < NNODES);

    for (int k0 = 0; k0 < K2; k0 += GBK) {
        const float* Asrc = (k0 < D) ? A : X;
        int kk = k0 & (D - 1);

        // ---- B staging: global_load_lds, pre-swizzled source (phys chunk sub holds kh=((row>>1)&3)^sub)
#pragma unroll
        for (int op = 0; op < 2; ++op) {
            int idx = op * 256 + wid * 64 + lane;
            int row = idx >> 2, sub = idx & 3;
            int kh = ((row >> 1) & 3) ^ sub;
            stage16(Wh + (size_t)(n0 + row) * K2 + k0 + kh * 8, Bh + (size_t)(op * 256 + wid * 64) * 8);
            stage16(Wl + (size_t)(n0 + row) * K2 + k0 + kh * 8, Bl + (size_t)(op * 256 + wid * 64) * 8);
        }

        // ---- A staging: f32 load -> hi/lo bf16 -> swizzled ds_write_b128
        {
            const float* base = Asrc + (size_t)gr * D + kk + acb * 8;
            float4 v0, v1, v2, v3;
            if (arow_ok) {
                v0 = *reinterpret_cast<const float4*>(base + 0);
                v1 = *reinterpret_cast<const float4*>(base + 4);
                v2 = *reinterpret_cast<const float4*>(base + 8);
                v3 = *reinterpret_cast<const float4*>(base + 12);
            } else {
                v0 = v1 = v2 = v3 = make_float4(0.f, 0.f, 0.f, 0.f);
            }
            float vv[16] = {v0.x, v0.y, v0.z, v0.w, v1.x, v1.y, v1.z, v1.w,
                            v2.x, v2.y, v2.z, v2.w, v3.x, v3.y, v3.z, v3.w};
            ushort hi[16], lo[16];
#pragma unroll
            for (int i = 0; i < 16; ++i) {
                hi[i] = f2bf(vv[i]);
                lo[i] = f2bf(vv[i] - bf2f(hi[i]));
            }
            int p0 = aswz ^ acb;
            int p1 = aswz ^ (acb + 1);
            *reinterpret_cast<uint4*>(&Ah[arow * GBK + p0 * 8]) = *reinterpret_cast<const uint4*>(&hi[0]);
            *reinterpret_cast<uint4*>(&Ah[arow * GBK + p1 * 8]) = *reinterpret_cast<const uint4*>(&hi[8]);
            *reinterpret_cast<uint4*>(&Al[arow * GBK + p0 * 8]) = *reinterpret_cast<const uint4*>(&lo[0]);
            *reinterpret_cast<uint4*>(&Al[arow * GBK + p1 * 8]) = *reinterpret_cast<const uint4*>(&lo[8]);
        }
        __syncthreads();

        // ---- fragment reads (swizzle-matched) + 48 MFMA
        bf16x8 ah[4], al[4], bh[4], bl[4];
        int half = lane >> 4;
#pragma unroll
        for (int m = 0; m < 4; ++m) {
            int row = wr * 64 + m * 16 + (lane & 15);
            int off = row * GBK + ((((row >> 1) & 3) ^ half) * 8);
            ah[m] = *reinterpret_cast<const bf16x8*>(&Ah[off]);
            al[m] = *reinterpret_cast<const bf16x8*>(&Al[off]);
        }
#pragma unroll
        for (int n = 0; n < 4; ++n) {
            int row = wc * 64 + n * 16 + (lane & 15);
            int off = row * GBK + ((((row >> 1) & 3) ^ half) * 8);
            bh[n] = *reinterpret_cast<const bf16x8*>(&Bh[off]);
            bl[n] = *reinterpret_cast<const bf16x8*>(&Bl[off]);
        }
#pragma unroll
        for (int m = 0; m < 4; ++m)
#pragma unroll
            for (int n = 0; n < 4; ++n) {
                acc[m][n] = __builtin_amdgcn_mfma_f32_16x16x32_bf16(ah[m], bh[n], acc[m][n], 0, 0, 0);
                acc[m][n] = __builtin_amdgcn_mfma_f32_16x16x32_bf16(ah[m], bl[n], acc[m][n], 0, 0, 0);
                acc[m][n] = __builtin_amdgcn_mfma_f32_16x16x32_bf16(al[m], bh[n], acc[m][n], 0, 0, 0);
            }
        __syncthreads();
    }

    // ---- epilogue: bias + relu -> f32
    int half = lane >> 4;
#pragma unroll
    for (int n = 0; n < 4; ++n) {
        int col = n0 + wc * 64 + n * 16 + (lane & 15);
        float bv = bias[col];
#pragma unroll
        for (int m = 0; m < 4; ++m) {
            int rbase = m0 + wr * 64 + m * 16 + half * 4;
#pragma unroll
            for (int j = 0; j < 4; ++j) {
                int r = rbase + j;
                if (r < NNODES)
                    out[(size_t)r * D + col] = fmaxf(acc[m][n][j] + bv, 0.f);
            }
        }
    }
}

// ---------------- fused pool + MLP1 + MLP2 (one block per graph) ----------------
__global__ __launch_bounds__(256)
void pool_mlp_kernel(const float* __restrict__ x, const int* __restrict__ gstart,
                     const float* __restrict__ W1, const float* __restrict__ b1,
                     const float* __restrict__ W2, const float* __restrict__ b2,
                     float* __restrict__ out) {
    __shared__ float red[4][D];    // pool partials, reused as [8][32] for mlp2
    __shared__ float p[D];         // pooled vector
    __shared__ float h[4 * D];     // mlp1 output (1024)
    int g = blockIdx.x;
    int t = threadIdx.x, wid = t >> 6, lane = t & 63;

    // pool (segmented, batch sorted)
    int beg = gstart[g], end = gstart[g + 1];
    float a0 = 0.f, a1 = 0.f, a2 = 0.f, a3 = 0.f;
    for (int r = beg + wid; r < end; r += 4) {
        float4 v = *reinterpret_cast<const float4*>(x + (size_t)r * D + lane * 4);
        a0 += v.x; a1 += v.y; a2 += v.z; a3 += v.w;
    }
    red[wid][lane * 4 + 0] = a0;
    red[wid][lane * 4 + 1] = a1;
    red[wid][lane * 4 + 2] = a2;
    red[wid][lane * 4 + 3] = a3;
    __syncthreads();
    p[t] = red[0][t] + red[1][t] + red[2][t] + red[3][t];
    __syncthreads();

    // mlp1: h = relu(p @ W1 + b1), thread t computes cols t*4..t*4+3
    float4 acc = make_float4(0.f, 0.f, 0.f, 0.f);
    for (int k = 0; k < D; ++k) {
        float4 w = *reinterpret_cast<const float4*>(W1 + (size_t)k * 1024 + t * 4);
        float pv = p[k];
        acc.x += pv * w.x; acc.y += pv * w.y; acc.z += pv * w.z; acc.w += pv * w.w;
    }
    float4 b = *reinterpret_cast<const float4*>(b1 + t * 4);
    h[t * 4 + 0] = fmaxf(acc.x + b.x, 0.f);
    h[t * 4 + 1] = fmaxf(acc.y + b.y, 0.f);
    h[t * 4 + 2] = fmaxf(acc.z + b.z, 0.f);
    h[t * 4 + 3] = fmaxf(acc.w + b.w, 0.f);
    __syncthreads();

    // mlp2: out = sigmoid(h @ W2 + b2)
    float* red2 = &red[0][0];      // reuse as [8][32]
    int c = t & 31, kc = t >> 5;
    float s = 0.f;
    for (int k = kc * 128; k < kc * 128 + 128; ++k)
        s += h[k] * W2[(size_t)k * 32 + c];
    red2[kc * 32 + c] = s;
    __syncthreads();
    if (t < 32) {
        float v = b2[t];
#pragma unroll
        for (int i = 0; i < 8; ++i) v += red2[i * 32 + t];
        out[(size_t)g * 32 + t] = 1.f / (1.f + expf(-v));
    }
}

extern "C" void kernel_launch(void* const* d_in, const int* in_sizes, int n_in,
                              void* d_out, int out_size, void* d_ws, size_t ws_size,
                              hipStream_t stream) {
    const float* x      = (const float*)d_in[0];
    const int*   ei     = (const int*)d_in[1];
    const int*   batch  = (const int*)d_in[2];
    const float* W_rel  = (const float*)d_in[3];
    const float* W_root = (const float*)d_in[4];
    const float* b_conv = (const float*)d_in[5];
    const float* W1     = (const float*)d_in[6];
    const float* b1     = (const float*)d_in[7];
    const float* W2     = (const float*)d_in[8];
    const float* b2     = (const float*)d_in[9];
    float* outp = (float*)d_out;

    const size_t NF = (size_t)MPAD * D;
    float* aggr   = (float*)d_ws;            // [MPAD][256]
    float* buf0   = aggr + NF;
    float* buf1   = buf0 + NF;
    ushort* Wh    = (ushort*)(buf1 + NF);    // 3*256*512 each
    ushort* Wl    = Wh + (size_t)NLAYERS * D * K2;
    int* deg       = (int*)(Wl + (size_t)NLAYERS * D * K2);
    int* row_start = deg + NNODES;           // NNODES+1
    int* cursor    = row_start + NNODES + 1;
    int* e_src     = cursor + NNODES;        // NEDGES
    int* gstart    = e_src + NEDGES;         // NGRAPH+1
    int* bsum      = gstart + NGRAPH + 1;    // NSCB
    int* boff      = bsum + NSCB;            // NSCB

    const int* srcp = ei;
    const int* dstp = ei + NEDGES;

    // CSR build (reused by all layers) — multi-block scan
    hipMemsetAsync(deg, 0, NNODES * sizeof(int), stream);
    hist_kernel<<<(NEDGES + 255) / 256, 256, 0, stream>>>(dstp, deg, NEDGES);
    scan_part_kernel<<<NSCB, SCB, 0, stream>>>(deg, bsum);
    scan_bsum_kernel<<<1, 256, 0, stream>>>(bsum, boff);
    scan_final_kernel<<<NSCB, SCB, 0, stream>>>(deg, boff, row_start, cursor);
    fill_kernel<<<(NEDGES + 255) / 256, 256, 0, stream>>>(srcp, dstp, cursor, e_src, NEDGES);
    gstart_kernel<<<3, 256, 0, stream>>>(batch, gstart);

    prep_w_kernel<<<(NLAYERS * D * K2 + 255) / 256, 256, 0, stream>>>(W_rel, W_root, Wh, Wl);

    int gatherBlocks = (NNODES + 3) / 4;
    dim3 ggrid(MPAD / GBM, D / GBN);

    const float* cur = x;
    float* nxt = buf0;
    for (int L = 0; L < NLAYERS; ++L) {
        gather_f32_kernel<<<gatherBlocks, 256, 0, stream>>>(cur, row_start, e_src, aggr);
        gemm_split_kernel<<<ggrid, 256, 0, stream>>>(aggr, cur,
                                                     Wh + (size_t)L * D * K2,
                                                     Wl + (size_t)L * D * K2,
                                                     b_conv + (size_t)L * D,
                                                     nxt);
        cur = nxt;
        nxt = (nxt == buf0) ? buf1 : buf0;
    }

    pool_mlp_kernel<<<NGRAPH, 256, 0, stream>>>(cur, gstart, W1, b1, W2, b2, outp);
}

// Round 13
// 431.206 us; speedup vs baseline: 1.3142x; 1.1043x over previous
//
#include <hip/hip_runtime.h>
#include <math.h>

#define NNODES 50000
#define MPAD   50048    // NNODES rounded up to 128
#define D      256
#define K2     512
#define NEDGES 300000
#define NGRAPH 512
#define NLAYERS 3

#define SCB    256
#define NSCB   ((NNODES + SCB - 1) / SCB)   // 196 blocks

typedef __bf16 bf16x8 __attribute__((ext_vector_type(8)));
typedef float  f32x4  __attribute__((ext_vector_type(4)));

__device__ __forceinline__ ushort f2bf(float f) {
    unsigned u = __float_as_uint(f);
    unsigned r = (u + 0x7FFFu + ((u >> 16) & 1u)) >> 16;   // RNE
    return (ushort)r;
}
__device__ __forceinline__ float bf2f(ushort b) {
    return __uint_as_float(((unsigned)b) << 16);
}

__device__ __forceinline__ void stage16(const ushort* g, ushort* l) {
    __builtin_amdgcn_global_load_lds(
        (const __attribute__((address_space(1))) unsigned*)g,
        (__attribute__((address_space(3))) unsigned*)l, 16, 0, 0);
}

// ---------------- CSR build ----------------
__global__ __launch_bounds__(256)
void hist_kernel(const int* __restrict__ dst, int* __restrict__ deg, int nE) {
    int e = blockIdx.x * 256 + threadIdx.x;
    if (e < nE) atomicAdd(&deg[dst[e]], 1);
}

__global__ __launch_bounds__(SCB)
void scan_part_kernel(const int* __restrict__ deg, int* __restrict__ bsum) {
    __shared__ int red[SCB];
    int t = threadIdx.x;
    int i = blockIdx.x * SCB + t;
    red[t] = (i < NNODES) ? deg[i] : 0;
    __syncthreads();
#pragma unroll
    for (int off = SCB / 2; off > 0; off >>= 1) {
        if (t < off) red[t] += red[t + off];
        __syncthreads();
    }
    if (t == 0) bsum[blockIdx.x] = red[0];
}

__global__ __launch_bounds__(256)
void scan_bsum_kernel(const int* __restrict__ bsum, int* __restrict__ boff) {
    __shared__ int p[256];
    int t = threadIdx.x;
    p[t] = (t < NSCB) ? bsum[t] : 0;
    __syncthreads();
    for (int off = 1; off < 256; off <<= 1) {
        int v = (t >= off) ? p[t - off] : 0;
        __syncthreads();
        p[t] += v;
        __syncthreads();
    }
    if (t < NSCB) boff[t] = (t == 0) ? 0 : p[t - 1];
}

__global__ __launch_bounds__(SCB)
void scan_final_kernel(const int* __restrict__ deg, const int* __restrict__ boff,
                       int* __restrict__ row_start, int* __restrict__ cursor) {
    __shared__ int p[SCB];
    int t = threadIdx.x;
    int i = blockIdx.x * SCB + t;
    int v = (i < NNODES) ? deg[i] : 0;
    p[t] = v;
    __syncthreads();
    for (int off = 1; off < SCB; off <<= 1) {
        int u = (t >= off) ? p[t - off] : 0;
        __syncthreads();
        p[t] += u;
        __syncthreads();
    }
    int excl = boff[blockIdx.x] + p[t] - v;
    if (i < NNODES) {
        row_start[i] = excl;
        cursor[i] = excl;
    }
    if (blockIdx.x == 0 && t == 0) row_start[NNODES] = NEDGES;
}

__global__ __launch_bounds__(256)
void fill_kernel(const int* __restrict__ src, const int* __restrict__ dst,
                 int* __restrict__ cursor, int* __restrict__ e_src, int nE) {
    int e = blockIdx.x * 256 + threadIdx.x;
    if (e < nE) {
        int pos = atomicAdd(&cursor[dst[e]], 1);
        e_src[pos] = src[e];
    }
}

// ---------------- graph segment starts (batch sorted) ----------------
__global__ __launch_bounds__(256)
void gstart_kernel(const int* __restrict__ batch, int* __restrict__ gstart) {
    int g = blockIdx.x * 256 + threadIdx.x;
    if (g > NGRAPH) return;
    if (g == NGRAPH) { gstart[g] = NNODES; return; }
    int lo = 0, hi = NNODES;
    while (lo < hi) { int mid = (lo + hi) >> 1; if (batch[mid] < g) lo = mid + 1; else hi = mid; }
    gstart[g] = lo;
}

// ---------------- weight prep: split into hi/lo bf16, [L][n][k] ----------------
__global__ __launch_bounds__(256)
void prep_w_kernel(const float* __restrict__ W_rel, const float* __restrict__ W_root,
                   ushort* __restrict__ Wh, ushort* __restrict__ Wl) {
    int i = blockIdx.x * 256 + threadIdx.x;
    if (i >= NLAYERS * D * K2) return;
    int L = i / (D * K2);
    int rem = i % (D * K2);
    int n = rem / K2;
    int k = rem % K2;
    float v = (k < D) ? W_rel[(size_t)L * D * D + (size_t)k * D + n]
                      : W_root[(size_t)L * D * D + (size_t)(k - D) * D + n];
    ushort hi = f2bf(v);
    float  lo = v - bf2f(hi);
    Wh[i] = hi;
    Wl[i] = f2bf(lo);
}

// ---------------- f32 gather-sum with 4-wide index unroll ----------------
__global__ __launch_bounds__(256)
void gather_f32_kernel(const float* __restrict__ x,
                       const int* __restrict__ row_start,
                       const int* __restrict__ e_src,
                       float* __restrict__ aggr) {
    int t = threadIdx.x;
    int n = blockIdx.x * 4 + (t >> 6);
    if (n >= NNODES) return;
    int lane = t & 63;
    int beg = row_start[n], end = row_start[n + 1];
    float a0 = 0.f, a1 = 0.f, a2 = 0.f, a3 = 0.f;
    int j = beg;
    for (; j + 4 <= end; j += 4) {
        int s0 = e_src[j], s1 = e_src[j + 1], s2 = e_src[j + 2], s3 = e_src[j + 3];
        float4 v0 = *reinterpret_cast<const float4*>(x + (size_t)s0 * D + lane * 4);
        float4 v1 = *reinterpret_cast<const float4*>(x + (size_t)s1 * D + lane * 4);
        float4 v2 = *reinterpret_cast<const float4*>(x + (size_t)s2 * D + lane * 4);
        float4 v3 = *reinterpret_cast<const float4*>(x + (size_t)s3 * D + lane * 4);
        a0 += v0.x + v1.x + v2.x + v3.x;
        a1 += v0.y + v1.y + v2.y + v3.y;
        a2 += v0.z + v1.z + v2.z + v3.z;
        a3 += v0.w + v1.w + v2.w + v3.w;
    }
    for (; j < end; ++j) {
        int s = e_src[j];
        float4 v = *reinterpret_cast<const float4*>(x + (size_t)s * D + lane * 4);
        a0 += v.x; a1 += v.y; a2 += v.z; a3 += v.w;
    }
    float4 o; o.x = a0; o.y = a1; o.z = a2; o.w = a3;
    *reinterpret_cast<float4*>(aggr + (size_t)n * D + lane * 4) = o;
}

// ---------------- split-bf16 MFMA GEMM: out = relu([A|X]@W^T + bias), f32 in/out ----------------
// GBM=64 tile: 1564 blocks (6.1/CU) for TLP-driven latency hiding; LDS 24 KB.
#define GBM 64
#define GBN 128
#define GBK 32

__global__ __launch_bounds__(256)
void gemm_split_kernel(const float* __restrict__ A,
                       const float* __restrict__ X,
                       const ushort* __restrict__ Wh,
                       const ushort* __restrict__ Wl,
                       const float* __restrict__ bias,
                       float* __restrict__ out) {
    __shared__ ushort Ah[GBM * GBK];   // 4 KB
    __shared__ ushort Al[GBM * GBK];   // 4 KB
    __shared__ ushort Bh[GBN * GBK];   // 8 KB
    __shared__ ushort Bl[GBN * GBK];   // 8 KB

    int t = threadIdx.x;
    int wid = t >> 6, lane = t & 63;
    int m0 = blockIdx.x * GBM;
    int n0 = blockIdx.y * GBN;
    int wr = wid >> 1, wc = wid & 1;   // wave tile: 32 rows x 64 cols
    int r = lane & 15, kq = lane >> 4;

    f32x4 acc[2][4];
#pragma unroll
    for (int m = 0; m < 2; ++m)
#pragma unroll
        for (int n = 0; n < 4; ++n)
            acc[m][n] = (f32x4){0.f, 0.f, 0.f, 0.f};

    // A staging: thread t owns row t>>2, one 8-elem k-chunk (t&3)
    int arow = t >> 2;
    int acb  = t & 3;
    int ap   = ((arow >> 1) & 3) ^ acb;     // swizzled physical chunk
    int gr   = m0 + arow;
    bool arow_ok = (gr < NNODES);

    for (int k0 = 0; k0 < K2; k0 += GBK) {
        const float* Asrc = (k0 < D) ? A : X;
        int kk = k0 & (D - 1);

        // ---- B staging: global_load_lds, pre-swizzled source
#pragma unroll
        for (int op = 0; op < 2; ++op) {
            int idx = op * 256 + t;
            int row = idx >> 2, sub = idx & 3;
            int kh = ((row >> 1) & 3) ^ sub;
            stage16(Wh + (size_t)(n0 + row) * K2 + k0 + kh * 8, Bh + (size_t)idx * 8);
            stage16(Wl + (size_t)(n0 + row) * K2 + k0 + kh * 8, Bl + (size_t)idx * 8);
        }

        // ---- A staging: 8 f32 -> hi/lo bf16 -> swizzled ds_write_b128
        {
            const float* base = Asrc + (size_t)gr * D + kk + acb * 8;
            float4 v0, v1;
            if (arow_ok) {
                v0 = *reinterpret_cast<const float4*>(base + 0);
                v1 = *reinterpret_cast<const float4*>(base + 4);
            } else {
                v0 = v1 = make_float4(0.f, 0.f, 0.f, 0.f);
            }
            float vv[8] = {v0.x, v0.y, v0.z, v0.w, v1.x, v1.y, v1.z, v1.w};
            ushort hi[8], lo[8];
#pragma unroll
            for (int i = 0; i < 8; ++i) {
                hi[i] = f2bf(vv[i]);
                lo[i] = f2bf(vv[i] - bf2f(hi[i]));
            }
            *reinterpret_cast<uint4*>(&Ah[arow * GBK + ap * 8]) = *reinterpret_cast<const uint4*>(hi);
            *reinterpret_cast<uint4*>(&Al[arow * GBK + ap * 8]) = *reinterpret_cast<const uint4*>(lo);
        }
        __syncthreads();

        // ---- fragment reads (swizzle-matched)
        bf16x8 ah[2], al[2], bh[4], bl[4];
#pragma unroll
        for (int m = 0; m < 2; ++m) {
            int row = wr * 32 + m * 16 + r;
            int off = row * GBK + ((((row >> 1) & 3) ^ kq) * 8);
            ah[m] = *reinterpret_cast<const bf16x8*>(&Ah[off]);
            al[m] = *reinterpret_cast<const bf16x8*>(&Al[off]);
        }
#pragma unroll
        for (int n = 0; n < 4; ++n) {
            int row = wc * 64 + n * 16 + r;
            int off = row * GBK + ((((row >> 1) & 3) ^ kq) * 8);
            bh[n] = *reinterpret_cast<const bf16x8*>(&Bh[off]);
            bl[n] = *reinterpret_cast<const bf16x8*>(&Bl[off]);
        }
        __syncthreads();   // fragments in VGPRs; LDS free for next stage

        // ---- 24 MFMA (runs while other waves stage the next tile)
#pragma unroll
        for (int m = 0; m < 2; ++m)
#pragma unroll
            for (int n = 0; n < 4; ++n) {
                acc[m][n] = __builtin_amdgcn_mfma_f32_16x16x32_bf16(ah[m], bh[n], acc[m][n], 0, 0, 0);
                acc[m][n] = __builtin_amdgcn_mfma_f32_16x16x32_bf16(ah[m], bl[n], acc[m][n], 0, 0, 0);
                acc[m][n] = __builtin_amdgcn_mfma_f32_16x16x32_bf16(al[m], bh[n], acc[m][n], 0, 0, 0);
            }
    }

    // ---- epilogue: bias + relu -> f32
#pragma unroll
    for (int n = 0; n < 4; ++n) {
        int col = n0 + wc * 64 + n * 16 + r;
        float bv = bias[col];
#pragma unroll
        for (int m = 0; m < 2; ++m) {
            int rbase = m0 + wr * 32 + m * 16 + kq * 4;
#pragma unroll
            for (int j = 0; j < 4; ++j) {
                int rr = rbase + j;
                if (rr < NNODES)
                    out[(size_t)rr * D + col] = fmaxf(acc[m][n][j] + bv, 0.f);
            }
        }
    }
}

// ---------------- fused pool + MLP1 + MLP2 (one block per graph) ----------------
__global__ __launch_bounds__(256)
void pool_mlp_kernel(const float* __restrict__ x, const int* __restrict__ gstart,
                     const float* __restrict__ W1, const float* __restrict__ b1,
                     const float* __restrict__ W2, const float* __restrict__ b2,
                     float* __restrict__ out) {
    __shared__ float red[4][D];    // pool partials, reused as [8][32] for mlp2
    __shared__ float p[D];         // pooled vector
    __shared__ float h[4 * D];     // mlp1 output (1024)
    int g = blockIdx.x;
    int t = threadIdx.x, wid = t >> 6, lane = t & 63;

    // pool (segmented, batch sorted)
    int beg = gstart[g], end = gstart[g + 1];
    float a0 = 0.f, a1 = 0.f, a2 = 0.f, a3 = 0.f;
    for (int r = beg + wid; r < end; r += 4) {
        float4 v = *reinterpret_cast<const float4*>(x + (size_t)r * D + lane * 4);
        a0 += v.x; a1 += v.y; a2 += v.z; a3 += v.w;
    }
    red[wid][lane * 4 + 0] = a0;
    red[wid][lane * 4 + 1] = a1;
    red[wid][lane * 4 + 2] = a2;
    red[wid][lane * 4 + 3] = a3;
    __syncthreads();
    p[t] = red[0][t] + red[1][t] + red[2][t] + red[3][t];
    __syncthreads();

    // mlp1: h = relu(p @ W1 + b1), thread t computes cols t*4..t*4+3
    float4 acc = make_float4(0.f, 0.f, 0.f, 0.f);
    for (int k = 0; k < D; ++k) {
        float4 w = *reinterpret_cast<const float4*>(W1 + (size_t)k * 1024 + t * 4);
        float pv = p[k];
        acc.x += pv * w.x; acc.y += pv * w.y; acc.z += pv * w.z; acc.w += pv * w.w;
    }
    float4 b = *reinterpret_cast<const float4*>(b1 + t * 4);
    h[t * 4 + 0] = fmaxf(acc.x + b.x, 0.f);
    h[t * 4 + 1] = fmaxf(acc.y + b.y, 0.f);
    h[t * 4 + 2] = fmaxf(acc.z + b.z, 0.f);
    h[t * 4 + 3] = fmaxf(acc.w + b.w, 0.f);
    __syncthreads();

    // mlp2: out = sigmoid(h @ W2 + b2)
    float* red2 = &red[0][0];      // reuse as [8][32]
    int c = t & 31, kc = t >> 5;
    float s = 0.f;
    for (int k = kc * 128; k < kc * 128 + 128; ++k)
        s += h[k] * W2[(size_t)k * 32 + c];
    red2[kc * 32 + c] = s;
    __syncthreads();
    if (t < 32) {
        float v = b2[t];
#pragma unroll
        for (int i = 0; i < 8; ++i) v += red2[i * 32 + t];
        out[(size_t)g * 32 + t] = 1.f / (1.f + expf(-v));
    }
}

extern "C" void kernel_launch(void* const* d_in, const int* in_sizes, int n_in,
                              void* d_out, int out_size, void* d_ws, size_t ws_size,
                              hipStream_t stream) {
    const float* x      = (const float*)d_in[0];
    const int*   ei     = (const int*)d_in[1];
    const int*   batch  = (const int*)d_in[2];
    const float* W_rel  = (const float*)d_in[3];
    const float* W_root = (const float*)d_in[4];
    const float* b_conv = (const float*)d_in[5];
    const float* W1     = (const float*)d_in[6];
    const float* b1     = (const float*)d_in[7];
    const float* W2     = (const float*)d_in[8];
    const float* b2     = (const float*)d_in[9];
    float* outp = (float*)d_out;

    const size_t NF = (size_t)MPAD * D;
    float* aggr   = (float*)d_ws;            // [MPAD][256]
    float* buf0   = aggr + NF;
    float* buf1   = buf0 + NF;
    ushort* Wh    = (ushort*)(buf1 + NF);    // 3*256*512 each
    ushort* Wl    = Wh + (size_t)NLAYERS * D * K2;
    int* deg       = (int*)(Wl + (size_t)NLAYERS * D * K2);
    int* row_start = deg + NNODES;           // NNODES+1
    int* cursor    = row_start + NNODES + 1;
    int* e_src     = cursor + NNODES;        // NEDGES
    int* gstart    = e_src + NEDGES;         // NGRAPH+1
    int* bsum      = gstart + NGRAPH + 1;    // NSCB
    int* boff      = bsum + NSCB;            // NSCB

    const int* srcp = ei;
    const int* dstp = ei + NEDGES;

    // CSR build (reused by all layers) — multi-block scan
    hipMemsetAsync(deg, 0, NNODES * sizeof(int), stream);
    hist_kernel<<<(NEDGES + 255) / 256, 256, 0, stream>>>(dstp, deg, NEDGES);
    scan_part_kernel<<<NSCB, SCB, 0, stream>>>(deg, bsum);
    scan_bsum_kernel<<<1, 256, 0, stream>>>(bsum, boff);
    scan_final_kernel<<<NSCB, SCB, 0, stream>>>(deg, boff, row_start, cursor);
    fill_kernel<<<(NEDGES + 255) / 256, 256, 0, stream>>>(srcp, dstp, cursor, e_src, NEDGES);
    gstart_kernel<<<3, 256, 0, stream>>>(batch, gstart);

    prep_w_kernel<<<(NLAYERS * D * K2 + 255) / 256, 256, 0, stream>>>(W_rel, W_root, Wh, Wl);

    int gatherBlocks = (NNODES + 3) / 4;
    dim3 ggrid(MPAD / GBM, D / GBN);

    const float* cur = x;
    float* nxt = buf0;
    for (int L = 0; L < NLAYERS; ++L) {
        gather_f32_kernel<<<gatherBlocks, 256, 0, stream>>>(cur, row_start, e_src, aggr);
        gemm_split_kernel<<<ggrid, 256, 0, stream>>>(aggr, cur,
                                                     Wh + (size_t)L * D * K2,
                                                     Wl + (size_t)L * D * K2,
                                                     b_conv + (size_t)L * D,
                                                     nxt);
        cur = nxt;
        nxt = (nxt == buf0) ? buf1 : buf0;
    }

    pool_mlp_kernel<<<NGRAPH, 256, 0, stream>>>(cur, gstart, W1, b1, W2, b2, outp);
}

// Round 14
// 409.827 us; speedup vs baseline: 1.3828x; 1.0522x over previous
//
#include <hip/hip_runtime.h>
#include <math.h>

#define NNODES 50000
#define MPAD   50048    // NNODES rounded up to 128
#define D      256
#define K2     512
#define NEDGES 300000
#define NGRAPH 512
#define NLAYERS 3

#define SCB    256
#define NSCB   ((NNODES + SCB - 1) / SCB)   // 196 blocks

typedef __bf16 bf16x8 __attribute__((ext_vector_type(8)));
typedef float  f32x4  __attribute__((ext_vector_type(4)));

__device__ __forceinline__ ushort f2bf(float f) {
    unsigned u = __float_as_uint(f);
    unsigned r = (u + 0x7FFFu + ((u >> 16) & 1u)) >> 16;   // RNE
    return (ushort)r;
}
__device__ __forceinline__ float bf2f(ushort b) {
    return __uint_as_float(((unsigned)b) << 16);
}

__device__ __forceinline__ void stage16(const ushort* g, ushort* l) {
    __builtin_amdgcn_global_load_lds(
        (const __attribute__((address_space(1))) unsigned*)g,
        (__attribute__((address_space(3))) unsigned*)l, 16, 0, 0);
}

// ---------------- CSR build ----------------
__global__ __launch_bounds__(256)
void hist_kernel(const int* __restrict__ dst, int* __restrict__ deg, int nE) {
    int e = blockIdx.x * 256 + threadIdx.x;
    if (e < nE) atomicAdd(&deg[dst[e]], 1);
}

__global__ __launch_bounds__(SCB)
void scan_part_kernel(const int* __restrict__ deg, int* __restrict__ bsum) {
    __shared__ int red[SCB];
    int t = threadIdx.x;
    int i = blockIdx.x * SCB + t;
    red[t] = (i < NNODES) ? deg[i] : 0;
    __syncthreads();
#pragma unroll
    for (int off = SCB / 2; off > 0; off >>= 1) {
        if (t < off) red[t] += red[t + off];
        __syncthreads();
    }
    if (t == 0) bsum[blockIdx.x] = red[0];
}

__global__ __launch_bounds__(256)
void scan_bsum_kernel(const int* __restrict__ bsum, int* __restrict__ boff) {
    __shared__ int p[256];
    int t = threadIdx.x;
    p[t] = (t < NSCB) ? bsum[t] : 0;
    __syncthreads();
    for (int off = 1; off < 256; off <<= 1) {
        int v = (t >= off) ? p[t - off] : 0;
        __syncthreads();
        p[t] += v;
        __syncthreads();
    }
    if (t < NSCB) boff[t] = (t == 0) ? 0 : p[t - 1];
}

__global__ __launch_bounds__(SCB)
void scan_final_kernel(const int* __restrict__ deg, const int* __restrict__ boff,
                       int* __restrict__ row_start, int* __restrict__ cursor) {
    __shared__ int p[SCB];
    int t = threadIdx.x;
    int i = blockIdx.x * SCB + t;
    int v = (i < NNODES) ? deg[i] : 0;
    p[t] = v;
    __syncthreads();
    for (int off = 1; off < SCB; off <<= 1) {
        int u = (t >= off) ? p[t - off] : 0;
        __syncthreads();
        p[t] += u;
        __syncthreads();
    }
    int excl = boff[blockIdx.x] + p[t] - v;
    if (i < NNODES) {
        row_start[i] = excl;
        cursor[i] = excl;
    }
    if (blockIdx.x == 0 && t == 0) row_start[NNODES] = NEDGES;
}

__global__ __launch_bounds__(256)
void fill_kernel(const int* __restrict__ src, const int* __restrict__ dst,
                 int* __restrict__ cursor, int* __restrict__ e_src, int nE) {
    int e = blockIdx.x * 256 + threadIdx.x;
    if (e < nE) {
        int pos = atomicAdd(&cursor[dst[e]], 1);
        e_src[pos] = src[e];
    }
}

// ---------------- graph segment starts (batch sorted) ----------------
__global__ __launch_bounds__(256)
void gstart_kernel(const int* __restrict__ batch, int* __restrict__ gstart) {
    int g = blockIdx.x * 256 + threadIdx.x;
    if (g > NGRAPH) return;
    if (g == NGRAPH) { gstart[g] = NNODES; return; }
    int lo = 0, hi = NNODES;
    while (lo < hi) { int mid = (lo + hi) >> 1; if (batch[mid] < g) lo = mid + 1; else hi = mid; }
    gstart[g] = lo;
}

// ---------------- weight prep: conv weights -> hi/lo bf16, [L][n][k] ----------------
__global__ __launch_bounds__(256)
void prep_w_kernel(const float* __restrict__ W_rel, const float* __restrict__ W_root,
                   ushort* __restrict__ Wh, ushort* __restrict__ Wl) {
    int i = blockIdx.x * 256 + threadIdx.x;
    if (i >= NLAYERS * D * K2) return;
    int L = i / (D * K2);
    int rem = i % (D * K2);
    int n = rem / K2;
    int k = rem % K2;
    float v = (k < D) ? W_rel[(size_t)L * D * D + (size_t)k * D + n]
                      : W_root[(size_t)L * D * D + (size_t)(k - D) * D + n];
    ushort hi = f2bf(v);
    float  lo = v - bf2f(hi);
    Wh[i] = hi;
    Wl[i] = f2bf(lo);
}

// ---------------- W1 prep: [256 k][1024 n] f32 -> hi/lo bf16 [1024 n][256 k] ----------------
__global__ __launch_bounds__(256)
void prep_w1_kernel(const float* __restrict__ W1,
                    ushort* __restrict__ W1h, ushort* __restrict__ W1l) {
    int i = blockIdx.x * 256 + threadIdx.x;
    if (i >= 1024 * D) return;
    int n = i >> 8;            // 0..1023
    int k = i & (D - 1);       // 0..255
    float v = W1[(size_t)k * 1024 + n];
    ushort hi = f2bf(v);
    W1h[i] = hi;
    W1l[i] = f2bf(v - bf2f(hi));
}

// ---------------- f32 gather-sum with 4-wide index unroll ----------------
__global__ __launch_bounds__(256)
void gather_f32_kernel(const float* __restrict__ x,
                       const int* __restrict__ row_start,
                       const int* __restrict__ e_src,
                       float* __restrict__ aggr) {
    int t = threadIdx.x;
    int n = blockIdx.x * 4 + (t >> 6);
    if (n >= NNODES) return;
    int lane = t & 63;
    int beg = row_start[n], end = row_start[n + 1];
    float a0 = 0.f, a1 = 0.f, a2 = 0.f, a3 = 0.f;
    int j = beg;
    for (; j + 4 <= end; j += 4) {
        int s0 = e_src[j], s1 = e_src[j + 1], s2 = e_src[j + 2], s3 = e_src[j + 3];
        float4 v0 = *reinterpret_cast<const float4*>(x + (size_t)s0 * D + lane * 4);
        float4 v1 = *reinterpret_cast<const float4*>(x + (size_t)s1 * D + lane * 4);
        float4 v2 = *reinterpret_cast<const float4*>(x + (size_t)s2 * D + lane * 4);
        float4 v3 = *reinterpret_cast<const float4*>(x + (size_t)s3 * D + lane * 4);
        a0 += v0.x + v1.x + v2.x + v3.x;
        a1 += v0.y + v1.y + v2.y + v3.y;
        a2 += v0.z + v1.z + v2.z + v3.z;
        a3 += v0.w + v1.w + v2.w + v3.w;
    }
    for (; j < end; ++j) {
        int s = e_src[j];
        float4 v = *reinterpret_cast<const float4*>(x + (size_t)s * D + lane * 4);
        a0 += v.x; a1 += v.y; a2 += v.z; a3 += v.w;
    }
    float4 o; o.x = a0; o.y = a1; o.z = a2; o.w = a3;
    *reinterpret_cast<float4*>(aggr + (size_t)n * D + lane * 4) = o;
}

// ---------------- split-bf16 MFMA GEMM: out = relu([A|X]@W^T + bias), f32 in/out ----------------
// GBM=64 tile: 1564 blocks (6.1/CU) for TLP-driven latency hiding; LDS 24 KB.
#define GBM 64
#define GBN 128
#define GBK 32

__global__ __launch_bounds__(256)
void gemm_split_kernel(const float* __restrict__ A,
                       const float* __restrict__ X,
                       const ushort* __restrict__ Wh,
                       const ushort* __restrict__ Wl,
                       const float* __restrict__ bias,
                       float* __restrict__ out) {
    __shared__ ushort Ah[GBM * GBK];   // 4 KB
    __shared__ ushort Al[GBM * GBK];   // 4 KB
    __shared__ ushort Bh[GBN * GBK];   // 8 KB
    __shared__ ushort Bl[GBN * GBK];   // 8 KB

    int t = threadIdx.x;
    int wid = t >> 6, lane = t & 63;
    int m0 = blockIdx.x * GBM;
    int n0 = blockIdx.y * GBN;
    int wr = wid >> 1, wc = wid & 1;   // wave tile: 32 rows x 64 cols
    int r = lane & 15, kq = lane >> 4;

    f32x4 acc[2][4];
#pragma unroll
    for (int m = 0; m < 2; ++m)
#pragma unroll
        for (int n = 0; n < 4; ++n)
            acc[m][n] = (f32x4){0.f, 0.f, 0.f, 0.f};

    // A staging: thread t owns row t>>2, one 8-elem k-chunk (t&3)
    int arow = t >> 2;
    int acb  = t & 3;
    int ap   = ((arow >> 1) & 3) ^ acb;     // swizzled physical chunk
    int gr   = m0 + arow;
    bool arow_ok = (gr < NNODES);

    for (int k0 = 0; k0 < K2; k0 += GBK) {
        const float* Asrc = (k0 < D) ? A : X;
        int kk = k0 & (D - 1);

        // ---- B staging: global_load_lds, pre-swizzled source
#pragma unroll
        for (int op = 0; op < 2; ++op) {
            int idx = op * 256 + t;
            int row = idx >> 2, sub = idx & 3;
            int kh = ((row >> 1) & 3) ^ sub;
            stage16(Wh + (size_t)(n0 + row) * K2 + k0 + kh * 8, Bh + (size_t)idx * 8);
            stage16(Wl + (size_t)(n0 + row) * K2 + k0 + kh * 8, Bl + (size_t)idx * 8);
        }

        // ---- A staging: 8 f32 -> hi/lo bf16 -> swizzled ds_write_b128
        {
            const float* base = Asrc + (size_t)gr * D + kk + acb * 8;
            float4 v0, v1;
            if (arow_ok) {
                v0 = *reinterpret_cast<const float4*>(base + 0);
                v1 = *reinterpret_cast<const float4*>(base + 4);
            } else {
                v0 = v1 = make_float4(0.f, 0.f, 0.f, 0.f);
            }
            float vv[8] = {v0.x, v0.y, v0.z, v0.w, v1.x, v1.y, v1.z, v1.w};
            ushort hi[8], lo[8];
#pragma unroll
            for (int i = 0; i < 8; ++i) {
                hi[i] = f2bf(vv[i]);
                lo[i] = f2bf(vv[i] - bf2f(hi[i]));
            }
            *reinterpret_cast<uint4*>(&Ah[arow * GBK + ap * 8]) = *reinterpret_cast<const uint4*>(hi);
            *reinterpret_cast<uint4*>(&Al[arow * GBK + ap * 8]) = *reinterpret_cast<const uint4*>(lo);
        }
        __syncthreads();

        // ---- fragment reads (swizzle-matched)
        bf16x8 ah[2], al[2], bh[4], bl[4];
#pragma unroll
        for (int m = 0; m < 2; ++m) {
            int row = wr * 32 + m * 16 + r;
            int off = row * GBK + ((((row >> 1) & 3) ^ kq) * 8);
            ah[m] = *reinterpret_cast<const bf16x8*>(&Ah[off]);
            al[m] = *reinterpret_cast<const bf16x8*>(&Al[off]);
        }
#pragma unroll
        for (int n = 0; n < 4; ++n) {
            int row = wc * 64 + n * 16 + r;
            int off = row * GBK + ((((row >> 1) & 3) ^ kq) * 8);
            bh[n] = *reinterpret_cast<const bf16x8*>(&Bh[off]);
            bl[n] = *reinterpret_cast<const bf16x8*>(&Bl[off]);
        }
        __syncthreads();   // fragments in VGPRs; LDS free for next stage

        // ---- 24 MFMA (runs while other waves stage the next tile)
#pragma unroll
        for (int m = 0; m < 2; ++m)
#pragma unroll
            for (int n = 0; n < 4; ++n) {
                acc[m][n] = __builtin_amdgcn_mfma_f32_16x16x32_bf16(ah[m], bh[n], acc[m][n], 0, 0, 0);
                acc[m][n] = __builtin_amdgcn_mfma_f32_16x16x32_bf16(ah[m], bl[n], acc[m][n], 0, 0, 0);
                acc[m][n] = __builtin_amdgcn_mfma_f32_16x16x32_bf16(al[m], bh[n], acc[m][n], 0, 0, 0);
            }
    }

    // ---- epilogue: bias + relu -> f32
#pragma unroll
    for (int n = 0; n < 4; ++n) {
        int col = n0 + wc * 64 + n * 16 + r;
        float bv = bias[col];
#pragma unroll
        for (int m = 0; m < 2; ++m) {
            int rbase = m0 + wr * 32 + m * 16 + kq * 4;
#pragma unroll
            for (int j = 0; j < 4; ++j) {
                int rr = rbase + j;
                if (rr < NNODES)
                    out[(size_t)rr * D + col] = fmaxf(acc[m][n][j] + bv, 0.f);
            }
        }
    }
}

// ---------------- segmented pool (f32, batch sorted, no atomics) ----------------
__global__ __launch_bounds__(256)
void pool_seg_kernel(const float* __restrict__ x, const int* __restrict__ gstart,
                     float* __restrict__ pooled) {
    __shared__ float red[4][D];
    int g = blockIdx.x;
    int t = threadIdx.x, wid = t >> 6, lane = t & 63;
    int beg = gstart[g], end = gstart[g + 1];
    float a0 = 0.f, a1 = 0.f, a2 = 0.f, a3 = 0.f;
    for (int r = beg + wid; r < end; r += 4) {
        float4 v = *reinterpret_cast<const float4*>(x + (size_t)r * D + lane * 4);
        a0 += v.x; a1 += v.y; a2 += v.z; a3 += v.w;
    }
    red[wid][lane * 4 + 0] = a0;
    red[wid][lane * 4 + 1] = a1;
    red[wid][lane * 4 + 2] = a2;
    red[wid][lane * 4 + 3] = a3;
    __syncthreads();
    float s = red[0][t] + red[1][t] + red[2][t] + red[3][t];
    pooled[(size_t)g * D + t] = s;
}

// ---------------- mlp1 as split-bf16 MFMA GEMM: h = relu(pooled @ W1 + b1) ----------------
// M=512 (graphs), N=1024, K=256. Tile 64x128, grid (8,8). All rows valid.
__global__ __launch_bounds__(256)
void mlp1_gemm_kernel(const float* __restrict__ P,
                      const ushort* __restrict__ W1h,
                      const ushort* __restrict__ W1l,
                      const float* __restrict__ b1,
                      float* __restrict__ h) {
    __shared__ ushort Ah[GBM * GBK];
    __shared__ ushort Al[GBM * GBK];
    __shared__ ushort Bh[GBN * GBK];
    __shared__ ushort Bl[GBN * GBK];

    int t = threadIdx.x;
    int wid = t >> 6, lane = t & 63;
    int m0 = blockIdx.x * GBM;
    int n0 = blockIdx.y * GBN;
    int wr = wid >> 1, wc = wid & 1;
    int r = lane & 15, kq = lane >> 4;

    f32x4 acc[2][4];
#pragma unroll
    for (int m = 0; m < 2; ++m)
#pragma unroll
        for (int n = 0; n < 4; ++n)
            acc[m][n] = (f32x4){0.f, 0.f, 0.f, 0.f};

    int arow = t >> 2;
    int acb  = t & 3;
    int ap   = ((arow >> 1) & 3) ^ acb;
    int gr   = m0 + arow;                   // < 512 always

    for (int k0 = 0; k0 < D; k0 += GBK) {   // K = 256 -> 8 steps
        // B staging (W1 hi/lo, [n][k] layout, stride D)
#pragma unroll
        for (int op = 0; op < 2; ++op) {
            int idx = op * 256 + t;
            int row = idx >> 2, sub = idx & 3;
            int kh = ((row >> 1) & 3) ^ sub;
            stage16(W1h + (size_t)(n0 + row) * D + k0 + kh * 8, Bh + (size_t)idx * 8);
            stage16(W1l + (size_t)(n0 + row) * D + k0 + kh * 8, Bl + (size_t)idx * 8);
        }
        // A staging (pooled f32 -> hi/lo)
        {
            const float* base = P + (size_t)gr * D + k0 + acb * 8;
            float4 v0 = *reinterpret_cast<const float4*>(base + 0);
            float4 v1 = *reinterpret_cast<const float4*>(base + 4);
            float vv[8] = {v0.x, v0.y, v0.z, v0.w, v1.x, v1.y, v1.z, v1.w};
            ushort hi[8], lo[8];
#pragma unroll
            for (int i = 0; i < 8; ++i) {
                hi[i] = f2bf(vv[i]);
                lo[i] = f2bf(vv[i] - bf2f(hi[i]));
            }
            *reinterpret_cast<uint4*>(&Ah[arow * GBK + ap * 8]) = *reinterpret_cast<const uint4*>(hi);
            *reinterpret_cast<uint4*>(&Al[arow * GBK + ap * 8]) = *reinterpret_cast<const uint4*>(lo);
        }
        __syncthreads();

        bf16x8 ah[2], al[2], bh[4], bl[4];
#pragma unroll
        for (int m = 0; m < 2; ++m) {
            int row = wr * 32 + m * 16 + r;
            int off = row * GBK + ((((row >> 1) & 3) ^ kq) * 8);
            ah[m] = *reinterpret_cast<const bf16x8*>(&Ah[off]);
            al[m] = *reinterpret_cast<const bf16x8*>(&Al[off]);
        }
#pragma unroll
        for (int n = 0; n < 4; ++n) {
            int row = wc * 64 + n * 16 + r;
            int off = row * GBK + ((((row >> 1) & 3) ^ kq) * 8);
            bh[n] = *reinterpret_cast<const bf16x8*>(&Bh[off]);
            bl[n] = *reinterpret_cast<const bf16x8*>(&Bl[off]);
        }
        __syncthreads();

#pragma unroll
        for (int m = 0; m < 2; ++m)
#pragma unroll
            for (int n = 0; n < 4; ++n) {
                acc[m][n] = __builtin_amdgcn_mfma_f32_16x16x32_bf16(ah[m], bh[n], acc[m][n], 0, 0, 0);
                acc[m][n] = __builtin_amdgcn_mfma_f32_16x16x32_bf16(ah[m], bl[n], acc[m][n], 0, 0, 0);
                acc[m][n] = __builtin_amdgcn_mfma_f32_16x16x32_bf16(al[m], bh[n], acc[m][n], 0, 0, 0);
            }
    }

    // epilogue: bias + relu -> h [512][1024]
#pragma unroll
    for (int n = 0; n < 4; ++n) {
        int col = n0 + wc * 64 + n * 16 + r;
        float bv = b1[col];
#pragma unroll
        for (int m = 0; m < 2; ++m) {
            int rbase = m0 + wr * 32 + m * 16 + kq * 4;
#pragma unroll
            for (int j = 0; j < 4; ++j) {
                int rr = rbase + j;
                h[(size_t)rr * 1024 + col] = fmaxf(acc[m][n][j] + bv, 0.f);
            }
        }
    }
}

// ---------------- MLP layer 2 (f32) ----------------
__global__ __launch_bounds__(256)
void mlp2_kernel(const float* __restrict__ h, const float* __restrict__ W2,
                 const float* __restrict__ b2, float* __restrict__ out) {
    __shared__ float red[8][32];
    int g = blockIdx.x, t = threadIdx.x;
    int c = t & 31, kc = t >> 5;
    float s = 0.f;
    const float* hr = h + (size_t)g * 1024;
#pragma unroll 4
    for (int k = kc * 128; k < kc * 128 + 128; ++k)
        s += hr[k] * W2[(size_t)k * 32 + c];
    red[kc][c] = s;
    __syncthreads();
    if (t < 32) {
        float v = b2[t];
#pragma unroll
        for (int i = 0; i < 8; ++i) v += red[i][t];
        out[(size_t)g * 32 + t] = 1.f / (1.f + expf(-v));
    }
}

extern "C" void kernel_launch(void* const* d_in, const int* in_sizes, int n_in,
                              void* d_out, int out_size, void* d_ws, size_t ws_size,
                              hipStream_t stream) {
    const float* x      = (const float*)d_in[0];
    const int*   ei     = (const int*)d_in[1];
    const int*   batch  = (const int*)d_in[2];
    const float* W_rel  = (const float*)d_in[3];
    const float* W_root = (const float*)d_in[4];
    const float* b_conv = (const float*)d_in[5];
    const float* W1     = (const float*)d_in[6];
    const float* b1     = (const float*)d_in[7];
    const float* W2     = (const float*)d_in[8];
    const float* b2     = (const float*)d_in[9];
    float* outp = (float*)d_out;

    const size_t NF = (size_t)MPAD * D;
    float* aggr   = (float*)d_ws;            // [MPAD][256]
    float* buf0   = aggr + NF;
    float* buf1   = buf0 + NF;
    ushort* Wh    = (ushort*)(buf1 + NF);    // 3*256*512 each
    ushort* Wl    = Wh + (size_t)NLAYERS * D * K2;
    ushort* W1h   = Wl + (size_t)NLAYERS * D * K2;   // 1024*256 each
    ushort* W1l   = W1h + (size_t)1024 * D;
    float* pooled = (float*)(W1l + (size_t)1024 * D);   // [512][256]
    float* hbuf   = pooled + (size_t)NGRAPH * D;        // [512][1024]
    int* deg       = (int*)(hbuf + (size_t)NGRAPH * 1024);
    int* row_start = deg + NNODES;           // NNODES+1
    int* cursor    = row_start + NNODES + 1;
    int* e_src     = cursor + NNODES;        // NEDGES
    int* gstart    = e_src + NEDGES;         // NGRAPH+1
    int* bsum      = gstart + NGRAPH + 1;    // NSCB
    int* boff      = bsum + NSCB;            // NSCB

    const int* srcp = ei;
    const int* dstp = ei + NEDGES;

    // CSR build (reused by all layers) — multi-block scan
    hipMemsetAsync(deg, 0, NNODES * sizeof(int), stream);
    hist_kernel<<<(NEDGES + 255) / 256, 256, 0, stream>>>(dstp, deg, NEDGES);
    scan_part_kernel<<<NSCB, SCB, 0, stream>>>(deg, bsum);
    scan_bsum_kernel<<<1, 256, 0, stream>>>(bsum, boff);
    scan_final_kernel<<<NSCB, SCB, 0, stream>>>(deg, boff, row_start, cursor);
    fill_kernel<<<(NEDGES + 255) / 256, 256, 0, stream>>>(srcp, dstp, cursor, e_src, NEDGES);
    gstart_kernel<<<3, 256, 0, stream>>>(batch, gstart);

    prep_w_kernel<<<(NLAYERS * D * K2 + 255) / 256, 256, 0, stream>>>(W_rel, W_root, Wh, Wl);
    prep_w1_kernel<<<(1024 * D + 255) / 256, 256, 0, stream>>>(W1, W1h, W1l);

    int gatherBlocks = (NNODES + 3) / 4;
    dim3 ggrid(MPAD / GBM, D / GBN);

    const float* cur = x;
    float* nxt = buf0;
    for (int L = 0; L < NLAYERS; ++L) {
        gather_f32_kernel<<<gatherBlocks, 256, 0, stream>>>(cur, row_start, e_src, aggr);
        gemm_split_kernel<<<ggrid, 256, 0, stream>>>(aggr, cur,
                                                     Wh + (size_t)L * D * K2,
                                                     Wl + (size_t)L * D * K2,
                                                     b_conv + (size_t)L * D,
                                                     nxt);
        cur = nxt;
        nxt = (nxt == buf0) ? buf1 : buf0;
    }

    pool_seg_kernel<<<NGRAPH, 256, 0, stream>>>(cur, gstart, pooled);
    mlp1_gemm_kernel<<<dim3(NGRAPH / GBM, 1024 / GBN), 256, 0, stream>>>(pooled, W1h, W1l, b1, hbuf);
    mlp2_kernel<<<NGRAPH, 256, 0, stream>>>(hbuf, W2, b2, outp);
}